// Round 3
// baseline (249.908 us; speedup 1.0000x reference)
//
#include <hip/hip_runtime.h>

// Problem constants
#define Bn     8
#define Cn     64
#define Hn     96
#define Wn     96
#define HW     9216        // Hn*Wn
#define K2     9
#define COUTn  64
#define KDIM   576         // Cn*K2
#define BLK_PIX 64         // pixels per block (4 waves x 16)
#define BLKS_PER_IMG 144   // HW / BLK_PIX
#define NT     256

typedef __attribute__((ext_vector_type(8))) short  short8;   // 8 bf16 = 4 VGPR
typedef __attribute__((ext_vector_type(4))) float  float4v;  // MFMA acc

__device__ __forceinline__ short f2bf(float f) {
    unsigned u = __builtin_bit_cast(unsigned, f);
    u += 0x7FFFu + ((u >> 16) & 1u);          // RNE (inputs finite)
    return (short)(u >> 16);
}

__global__ void convert_weight(const float* __restrict__ w, short* __restrict__ wbf) {
    int i = blockIdx.x * 256 + threadIdx.x;
    if (i < COUTn * KDIM) wbf[i] = f2bf(w[i]);
}

struct CornerBuf { float v0[8], v1[8], v2[8], v3[8]; };

__global__ __launch_bounds__(NT, 4)
void deform_conv_mfma(const float* __restrict__ x,
                      const float* __restrict__ offset,
                      const short* __restrict__ wbf,
                      float* __restrict__ out) {
    __shared__ int    sA[K2 * BLK_PIX];     // 2.25 KB packed corner addr
    __shared__ float4 sW[K2 * BLK_PIX];     // 9 KB bilinear weights

    const int tid  = threadIdx.x;
    // XCD swizzle: round-robin dispatch puts blockIdx%8 on one XCD ->
    // all 144 tiles of image b share that XCD's L2 (x-plane 2.36 MB < 4 MB)
    const int b    = blockIdx.x & 7;
    const int pix0 = (blockIdx.x >> 3) * BLK_PIX;

    const float* xb   = x + (size_t)b * (Cn * HW);
    const float* offb = offset + (size_t)b * (2 * K2 * HW);

    // ---- Phase 0: sampling metadata for (kk, pl) -> LDS, one barrier ----
    for (int e = tid; e < K2 * BLK_PIX; e += NT) {
        int kk = e >> 6;             // e / 64
        int pl = e & 63;
        int pix = pix0 + pl;
        int h = pix / 96, w = pix - h * 96;
        float offy = offb[(2 * kk) * HW + pix];
        float offx = offb[(2 * kk + 1) * HW + pix];
        float py = (float)(h - 1 + kk / 3) + offy;
        float px = (float)(w - 1 + kk % 3) + offx;
        float y0f = floorf(py), x0f = floorf(px);
        float ly = py - y0f, lx = px - x0f;
        int y0 = (int)y0f, x0 = (int)x0f;
        float vy0 = ((unsigned)y0 < 96u) ? 1.f : 0.f;
        float vy1 = ((unsigned)(y0 + 1) < 96u) ? 1.f : 0.f;
        float vx0 = ((unsigned)x0 < 96u) ? 1.f : 0.f;
        float vx1 = ((unsigned)(x0 + 1) < 96u) ? 1.f : 0.f;
        float w00 = (1.f - ly) * (1.f - lx) * vy0 * vx0;
        float w01 = (1.f - ly) * lx         * vy0 * vx1;
        float w10 = ly * (1.f - lx)         * vy1 * vx0;
        float w11 = ly * lx                 * vy1 * vx1;
        int y0c = min(max(y0, 0), 95);
        int x0c = min(max(x0, 0), 95);
        int dx = min(max(x0 + 1, 0), 95) - x0c;   // 0 or 1
        int dy = min(max(y0 + 1, 0), 95) - y0c;   // 0 or 1
        sA[e] = (y0c * 96 + x0c) | (dx << 14) | (dy << 15);
        sW[e] = make_float4(w00, w01, w10, w11);
    }
    __syncthreads();   // the only barrier

    const int lane = tid & 63;
    const int wv   = tid >> 6;
    const int q    = lane >> 4;          // quad 0..3
    const int r    = lane & 15;          // 0..15
    const int plw  = wv * 16 + r;        // this lane's B-column pixel (local)

    float4v acc0 = {0.f,0.f,0.f,0.f};
    float4v acc1 = {0.f,0.f,0.f,0.f};
    float4v acc2 = {0.f,0.f,0.f,0.f};
    float4v acc3 = {0.f,0.f,0.f,0.f};

    // Issue the 32 corner gathers for k-block starting at kb into buf.
    auto issue = [&](int kb, CornerBuf& buf) {
        #pragma unroll
        for (int j = 0; j < 8; ++j) {
            unsigned kg = (unsigned)(kb + q * 8 + j);
            unsigned c  = kg / 9u;
            unsigned kk = kg - c * 9u;
            int pack  = sA[(int)kk * BLK_PIX + plw];
            int a00   = pack & 16383;
            int dxv   = (pack >> 14) & 1;
            int dy96  = ((pack >> 15) & 1) * 96;
            const float* xc = xb + (size_t)c * HW;
            buf.v0[j] = xc[a00];
            buf.v1[j] = xc[a00 + dxv];
            buf.v2[j] = xc[a00 + dy96];
            buf.v3[j] = xc[a00 + dy96 + dxv];
        }
    };

    // Consume buf: bilinear combine -> bf16 B-frag -> 4 MFMAs.
    auto consume = [&](int kb, CornerBuf& buf) {
        short8 bq;
        #pragma unroll
        for (int j = 0; j < 8; ++j) {
            unsigned kg = (unsigned)(kb + q * 8 + j);
            unsigned c  = kg / 9u;
            unsigned kk = kg - c * 9u;
            float4 w4 = sW[(int)kk * BLK_PIX + plw];
            float v = fmaf(w4.x, buf.v0[j],
                      fmaf(w4.y, buf.v1[j],
                      fmaf(w4.z, buf.v2[j],
                           w4.w * buf.v3[j])));
            bq[j] = f2bf(v);
        }
        const short* wp = wbf + (size_t)r * KDIM + kb + q * 8;
        short8 a0 = *(const short8*)(wp + 0 * 16 * KDIM);
        short8 a1 = *(const short8*)(wp + 1 * 16 * KDIM);
        short8 a2 = *(const short8*)(wp + 2 * 16 * KDIM);
        short8 a3 = *(const short8*)(wp + 3 * 16 * KDIM);
        acc0 = __builtin_amdgcn_mfma_f32_16x16x32_bf16(a0, bq, acc0, 0, 0, 0);
        acc1 = __builtin_amdgcn_mfma_f32_16x16x32_bf16(a1, bq, acc1, 0, 0, 0);
        acc2 = __builtin_amdgcn_mfma_f32_16x16x32_bf16(a2, bq, acc2, 0, 0, 0);
        acc3 = __builtin_amdgcn_mfma_f32_16x16x32_bf16(a3, bq, acc3, 0, 0, 0);
    };

    // Software pipeline, prefetch distance 1, ping-pong buffers (18 = 2*9)
    CornerBuf bufA, bufB;
    issue(0, bufA);
    for (int ks = 0; ks < 18; ks += 2) {
        issue((ks + 1) * 32, bufB);
        consume(ks * 32, bufA);
        if (ks + 2 < 18) issue((ks + 2) * 32, bufA);
        consume((ks + 1) * 32, bufB);
    }

    // ---- Store: D[row = cout = mt*16 + q*4 + reg][col = pixel] ----
    float* ob = out + (size_t)b * COUTn * HW + pix0 + plw;
    #pragma unroll
    for (int mt = 0; mt < 4; ++mt) {
        float4v a = (mt == 0) ? acc0 : (mt == 1) ? acc1 : (mt == 2) ? acc2 : acc3;
        float* p = ob + (size_t)(mt * 16 + q * 4) * HW;
        p[0 * HW] = a[0];
        p[1 * HW] = a[1];
        p[2 * HW] = a[2];
        p[3 * HW] = a[3];
    }
}

extern "C" void kernel_launch(void* const* d_in, const int* in_sizes, int n_in,
                              void* d_out, int out_size, void* d_ws, size_t ws_size,
                              hipStream_t stream) {
    const float* x      = (const float*)d_in[0];
    const float* offset = (const float*)d_in[1];
    const float* weight = (const float*)d_in[2];
    float* out = (float*)d_out;
    short* wbf = (short*)d_ws;   // 64*576*2 = 73728 B

    convert_weight<<<dim3((COUTn * KDIM + 255) / 256), dim3(256), 0, stream>>>(weight, wbf);
    deform_conv_mfma<<<dim3(Bn * BLKS_PER_IMG), dim3(NT), 0, stream>>>(x, offset, wbf, out);
}

// Round 4
// 212.067 us; speedup vs baseline: 1.1784x; 1.1784x over previous
//
#include <hip/hip_runtime.h>

// Problem constants
#define Bn     8
#define Cn     64
#define Hn     96
#define Wn     96
#define HW     9216        // Hn*Wn
#define K2     9
#define COUTn  64
#define KDIM   576         // Cn*K2
#define BLK_PIX 64         // pixels per block (4 waves x 16)
#define BLKS_PER_IMG 144   // HW / BLK_PIX
#define NT     256
#define ROWF   (Wn*Cn)     // 6144 floats per HWC image row
#define XT_FLOATS (Bn*HW*Cn)
#define XT_BYTES  ((size_t)XT_FLOATS*4)   // 18,874,368

typedef __attribute__((ext_vector_type(8))) short  short8;   // 8 bf16 = 4 VGPR
typedef __attribute__((ext_vector_type(4))) float  float4v;  // MFMA acc

__device__ __forceinline__ short f2bf(float f) {
    unsigned u = __builtin_bit_cast(unsigned, f);
    u += 0x7FFFu + ((u >> 16) & 1u);          // RNE (inputs finite)
    return (short)(u >> 16);
}

// ---- Pre-pass A: weight -> bf16, permuted so K index = kk*64 + c ----
__global__ void prep_weight(const float* __restrict__ w, short* __restrict__ wperm) {
    int i = blockIdx.x * 256 + threadIdx.x;
    if (i >= COUTn * KDIM) return;
    int cout = i / KDIM;
    int rem  = i - cout * KDIM;
    int kk = rem >> 6;          // 0..8
    int c  = rem & 63;
    wperm[i] = f2bf(w[cout * KDIM + c * K2 + kk]);
}

// ---- Pre-pass A2: weight -> bf16, natural order (fallback path) ----
__global__ void convert_weight(const float* __restrict__ w, short* __restrict__ wbf) {
    int i = blockIdx.x * 256 + threadIdx.x;
    if (i < COUTn * KDIM) wbf[i] = f2bf(w[i]);
}

// ---- Pre-pass B: x NCHW -> NHWC (f32) ----
__global__ __launch_bounds__(NT)
void transpose_x(const float* __restrict__ x, float* __restrict__ xt) {
    __shared__ float tile[Cn * 65];     // 16.6 KB
    const int t    = threadIdx.x;
    const int lane = t & 63, wv = t >> 6;
    const int b    = blockIdx.x & 7;
    const int pix0 = (blockIdx.x >> 3) * BLK_PIX;

    #pragma unroll
    for (int i = 0; i < 16; ++i) {
        int c = wv + i * 4;
        tile[c * 65 + lane] = x[((size_t)b * Cn + c) * HW + pix0 + lane];
    }
    __syncthreads();
    #pragma unroll
    for (int pass = 0; pass < 4; ++pass) {
        int px = wv * 16 + pass * 4 + (lane >> 4);
        int c4 = (lane & 15) * 4;
        float4 v = make_float4(tile[(c4 + 0) * 65 + px],
                               tile[(c4 + 1) * 65 + px],
                               tile[(c4 + 2) * 65 + px],
                               tile[(c4 + 3) * 65 + px]);
        *(float4*)&xt[((size_t)b * HW + pix0 + px) * Cn + c4] = v;
    }
}

// ---- Main kernel: HWC gathers, full-line efficient ----
__global__ __launch_bounds__(NT, 4)
void deform_conv_hwc(const float* __restrict__ xt,
                     const float* __restrict__ offset,
                     const short* __restrict__ wperm,
                     float* __restrict__ out) {
    __shared__ int    sA[K2 * BLK_PIX];   // 2.25 KB
    __shared__ float4 sW[K2 * BLK_PIX];   // 9 KB
    __shared__ float  sC[COUTn * 68];     // 17.4 KB epilogue staging

    const int tid  = threadIdx.x;
    const int b    = blockIdx.x & 7;                 // XCD swizzle
    const int pix0 = (blockIdx.x >> 3) * BLK_PIX;

    const float* xb   = xt + (size_t)b * (HW * Cn);
    const float* offb = offset + (size_t)b * (2 * K2 * HW);

    // ---- Phase 0: sampling metadata per (kk, pixel) ----
    for (int e = tid; e < K2 * BLK_PIX; e += NT) {
        int kk = e >> 6;
        int pl = e & 63;
        int pix = pix0 + pl;
        int h = pix / 96, w = pix - h * 96;
        float offy = offb[(2 * kk) * HW + pix];
        float offx = offb[(2 * kk + 1) * HW + pix];
        float py = (float)(h - 1 + kk / 3) + offy;
        float px = (float)(w - 1 + kk % 3) + offx;
        float y0f = floorf(py), x0f = floorf(px);
        float ly = py - y0f, lx = px - x0f;
        int y0 = (int)y0f, x0 = (int)x0f;
        float vy0 = ((unsigned)y0 < 96u) ? 1.f : 0.f;
        float vy1 = ((unsigned)(y0 + 1) < 96u) ? 1.f : 0.f;
        float vx0 = ((unsigned)x0 < 96u) ? 1.f : 0.f;
        float vx1 = ((unsigned)(x0 + 1) < 96u) ? 1.f : 0.f;
        float w00 = (1.f - ly) * (1.f - lx) * vy0 * vx0;
        float w01 = (1.f - ly) * lx         * vy0 * vx1;
        float w10 = ly * (1.f - lx)         * vy1 * vx0;
        float w11 = ly * lx                 * vy1 * vx1;
        int y0c = min(max(y0, 0), 95);
        int x0c = min(max(x0, 0), 95);
        int dx = min(max(x0 + 1, 0), 95) - x0c;   // 0 or 1
        int dy = min(max(y0 + 1, 0), 95) - y0c;   // 0 or 1
        sA[e] = (y0c * 96 + x0c) | (dx << 14) | (dy << 15);
        sW[e] = make_float4(w00, w01, w10, w11);
    }
    __syncthreads();

    const int lane = tid & 63;
    const int wv   = tid >> 6;
    const int q    = lane >> 4;          // quad 0..3
    const int r    = lane & 15;          // 0..15
    const int plw  = wv * 16 + r;        // B-column pixel (local)

    float4v acc0 = {0.f,0.f,0.f,0.f};
    float4v acc1 = {0.f,0.f,0.f,0.f};
    float4v acc2 = {0.f,0.f,0.f,0.f};
    float4v acc3 = {0.f,0.f,0.f,0.f};

    const short* wbase = wperm + (size_t)r * KDIM + q * 8;

    for (int kk = 0; kk < 9; ++kk) {
        const int idx = kk * BLK_PIX + plw;
        const int pack  = sA[idx];
        const float4 w4 = sW[idx];
        const int a00p = pack & 16383;
        const int dxs  = ((pack >> 14) & 1) * Cn;     // +1 col = +64 floats
        const int dys  = ((pack >> 15) & 1) * ROWF;   // +1 row
        const float* v00 = xb + (size_t)a00p * Cn;
        const float* v01 = v00 + dxs;
        const float* v10 = v00 + dys;
        const float* v11 = v10 + dxs;

        #pragma unroll
        for (int ch = 0; ch < 2; ++ch) {
            const int co = ch * 32 + q * 8;
            // 8 channels x 4 corners, all 16B-aligned dwordx4
            float4 c00a = *(const float4*)(v00 + co), c00b = *(const float4*)(v00 + co + 4);
            float4 c01a = *(const float4*)(v01 + co), c01b = *(const float4*)(v01 + co + 4);
            float4 c10a = *(const float4*)(v10 + co), c10b = *(const float4*)(v10 + co + 4);
            float4 c11a = *(const float4*)(v11 + co), c11b = *(const float4*)(v11 + co + 4);

            short8 bq;
            bq[0] = f2bf(fmaf(w4.x,c00a.x, fmaf(w4.y,c01a.x, fmaf(w4.z,c10a.x, w4.w*c11a.x))));
            bq[1] = f2bf(fmaf(w4.x,c00a.y, fmaf(w4.y,c01a.y, fmaf(w4.z,c10a.y, w4.w*c11a.y))));
            bq[2] = f2bf(fmaf(w4.x,c00a.z, fmaf(w4.y,c01a.z, fmaf(w4.z,c10a.z, w4.w*c11a.z))));
            bq[3] = f2bf(fmaf(w4.x,c00a.w, fmaf(w4.y,c01a.w, fmaf(w4.z,c10a.w, w4.w*c11a.w))));
            bq[4] = f2bf(fmaf(w4.x,c00b.x, fmaf(w4.y,c01b.x, fmaf(w4.z,c10b.x, w4.w*c11b.x))));
            bq[5] = f2bf(fmaf(w4.x,c00b.y, fmaf(w4.y,c01b.y, fmaf(w4.z,c10b.y, w4.w*c11b.y))));
            bq[6] = f2bf(fmaf(w4.x,c00b.z, fmaf(w4.y,c01b.z, fmaf(w4.z,c10b.z, w4.w*c11b.z))));
            bq[7] = f2bf(fmaf(w4.x,c00b.w, fmaf(w4.y,c01b.w, fmaf(w4.z,c10b.w, w4.w*c11b.w))));

            const short* wp = wbase + kk * 64 + ch * 32;
            short8 a0 = *(const short8*)(wp + 0  * 16 * KDIM);
            short8 a1 = *(const short8*)(wp + 1  * 16 * KDIM);
            short8 a2 = *(const short8*)(wp + 2  * 16 * KDIM);
            short8 a3 = *(const short8*)(wp + 3  * 16 * KDIM);

            acc0 = __builtin_amdgcn_mfma_f32_16x16x32_bf16(a0, bq, acc0, 0, 0, 0);
            acc1 = __builtin_amdgcn_mfma_f32_16x16x32_bf16(a1, bq, acc1, 0, 0, 0);
            acc2 = __builtin_amdgcn_mfma_f32_16x16x32_bf16(a2, bq, acc2, 0, 0, 0);
            acc3 = __builtin_amdgcn_mfma_f32_16x16x32_bf16(a3, bq, acc3, 0, 0, 0);
        }
    }

    // ---- Epilogue: stage through LDS for full-line stores ----
    #pragma unroll
    for (int mt = 0; mt < 4; ++mt) {
        float4v a = (mt == 0) ? acc0 : (mt == 1) ? acc1 : (mt == 2) ? acc2 : acc3;
        int cout = mt * 16 + q * 4;
        #pragma unroll
        for (int reg = 0; reg < 4; ++reg)
            sC[(cout + reg) * 68 + plw] = a[reg];
    }
    __syncthreads();

    #pragma unroll
    for (int i = 0; i < 4; ++i) {
        int cout = (tid >> 4) + i * 16;
        int px4  = (tid & 15) * 4;
        float4 v = *(const float4*)&sC[cout * 68 + px4];
        *(float4*)&out[((size_t)(b * COUTn + cout)) * HW + pix0 + px4] = v;
    }
}

// ---- Fallback (round-2 structure, NCHW gathers) if ws too small ----
__global__ __launch_bounds__(NT, 4)
void deform_conv_nchw(const float* __restrict__ x,
                      const float* __restrict__ offset,
                      const short* __restrict__ wbf,
                      float* __restrict__ out) {
    __shared__ int    sA[K2 * BLK_PIX];
    __shared__ float4 sW[K2 * BLK_PIX];

    const int tid  = threadIdx.x;
    const int b    = blockIdx.x / BLKS_PER_IMG;
    const int pix0 = (blockIdx.x - b * BLKS_PER_IMG) * BLK_PIX;

    const float* xb   = x + (size_t)b * (Cn * HW);
    const float* offb = offset + (size_t)b * (2 * K2 * HW);

    for (int e = tid; e < K2 * BLK_PIX; e += NT) {
        int kk = e >> 6;
        int pl = e & 63;
        int pix = pix0 + pl;
        int h = pix / 96, w = pix - h * 96;
        float offy = offb[(2 * kk) * HW + pix];
        float offx = offb[(2 * kk + 1) * HW + pix];
        float py = (float)(h - 1 + kk / 3) + offy;
        float px = (float)(w - 1 + kk % 3) + offx;
        float y0f = floorf(py), x0f = floorf(px);
        float ly = py - y0f, lx = px - x0f;
        int y0 = (int)y0f, x0 = (int)x0f;
        float vy0 = ((unsigned)y0 < 96u) ? 1.f : 0.f;
        float vy1 = ((unsigned)(y0 + 1) < 96u) ? 1.f : 0.f;
        float vx0 = ((unsigned)x0 < 96u) ? 1.f : 0.f;
        float vx1 = ((unsigned)(x0 + 1) < 96u) ? 1.f : 0.f;
        float w00 = (1.f - ly) * (1.f - lx) * vy0 * vx0;
        float w01 = (1.f - ly) * lx         * vy0 * vx1;
        float w10 = ly * (1.f - lx)         * vy1 * vx0;
        float w11 = ly * lx                 * vy1 * vx1;
        int y0c = min(max(y0, 0), 95);
        int x0c = min(max(x0, 0), 95);
        int dx = min(max(x0 + 1, 0), 95) - x0c;
        int dy = min(max(y0 + 1, 0), 95) - y0c;
        sA[e] = (y0c * 96 + x0c) | (dx << 14) | (dy << 15);
        sW[e] = make_float4(w00, w01, w10, w11);
    }
    __syncthreads();

    const int lane = tid & 63;
    const int wv   = tid >> 6;
    const int q    = lane >> 4;
    const int r    = lane & 15;
    const int plw  = wv * 16 + r;

    float4v acc0 = {0.f,0.f,0.f,0.f};
    float4v acc1 = {0.f,0.f,0.f,0.f};
    float4v acc2 = {0.f,0.f,0.f,0.f};
    float4v acc3 = {0.f,0.f,0.f,0.f};

    for (int ks = 0; ks < 18; ++ks) {
        const int kb = ks * 32;
        const short* wp = wbf + (size_t)r * KDIM + kb + q * 8;
        short8 a0 = *(const short8*)(wp + 0 * 16 * KDIM);
        short8 a1 = *(const short8*)(wp + 1 * 16 * KDIM);
        short8 a2 = *(const short8*)(wp + 2 * 16 * KDIM);
        short8 a3 = *(const short8*)(wp + 3 * 16 * KDIM);

        short8 bq;
        #pragma unroll
        for (int j = 0; j < 8; ++j) {
            unsigned kg = (unsigned)(kb + q * 8 + j);
            unsigned c  = kg / 9u;
            unsigned kk = kg - c * 9u;
            int idx = (int)kk * BLK_PIX + plw;
            int pack  = sA[idx];
            float4 w4 = sW[idx];
            int a00  = pack & 16383;
            int dxv  = (pack >> 14) & 1;
            int dy96 = ((pack >> 15) & 1) * 96;
            const float* xc = xb + (size_t)c * HW;
            float v = w4.x * xc[a00]
                    + w4.y * xc[a00 + dxv]
                    + w4.z * xc[a00 + dy96]
                    + w4.w * xc[a00 + dy96 + dxv];
            bq[j] = f2bf(v);
        }
        acc0 = __builtin_amdgcn_mfma_f32_16x16x32_bf16(a0, bq, acc0, 0, 0, 0);
        acc1 = __builtin_amdgcn_mfma_f32_16x16x32_bf16(a1, bq, acc1, 0, 0, 0);
        acc2 = __builtin_amdgcn_mfma_f32_16x16x32_bf16(a2, bq, acc2, 0, 0, 0);
        acc3 = __builtin_amdgcn_mfma_f32_16x16x32_bf16(a3, bq, acc3, 0, 0, 0);
    }

    float* ob = out + (size_t)b * COUTn * HW + pix0 + plw;
    #pragma unroll
    for (int mt = 0; mt < 4; ++mt) {
        float4v a = (mt == 0) ? acc0 : (mt == 1) ? acc1 : (mt == 2) ? acc2 : acc3;
        float* p = ob + (size_t)(mt * 16 + q * 4) * HW;
        p[0 * HW] = a[0];
        p[1 * HW] = a[1];
        p[2 * HW] = a[2];
        p[3 * HW] = a[3];
    }
}

extern "C" void kernel_launch(void* const* d_in, const int* in_sizes, int n_in,
                              void* d_out, int out_size, void* d_ws, size_t ws_size,
                              hipStream_t stream) {
    const float* x      = (const float*)d_in[0];
    const float* offset = (const float*)d_in[1];
    const float* weight = (const float*)d_in[2];
    float* out = (float*)d_out;

    const size_t need = XT_BYTES + (size_t)COUTn * KDIM * 2;
    if (ws_size >= need) {
        float* xt    = (float*)d_ws;
        short* wperm = (short*)((char*)d_ws + XT_BYTES);
        prep_weight<<<dim3((COUTn * KDIM + 255) / 256), dim3(256), 0, stream>>>(weight, wperm);
        transpose_x<<<dim3(Bn * BLKS_PER_IMG), dim3(NT), 0, stream>>>(x, xt);
        deform_conv_hwc<<<dim3(Bn * BLKS_PER_IMG), dim3(NT), 0, stream>>>(xt, offset, wperm, out);
    } else {
        short* wbf = (short*)d_ws;   // 73,728 B
        convert_weight<<<dim3((COUTn * KDIM + 255) / 256), dim3(256), 0, stream>>>(weight, wbf);
        deform_conv_nchw<<<dim3(Bn * BLKS_PER_IMG), dim3(NT), 0, stream>>>(x, offset, wbf, out);
    }
}

// Round 5
// 157.016 us; speedup vs baseline: 1.5916x; 1.3506x over previous
//
#include <hip/hip_runtime.h>

// Problem constants
#define Bn     8
#define Cn     64
#define Hn     96
#define Wn     96
#define HW     9216        // Hn*Wn
#define K2     9
#define COUTn  64
#define KDIM   576         // Cn*K2
#define BLK_PIX 64         // pixels per block (4 waves x 16)
#define BLKS_PER_IMG 144   // HW / BLK_PIX
#define NT     256
#define RECS   64          // shorts per HWC bf16 pixel record (128 B)
#define ROWS   (Wn*RECS)   // shorts per image row = 6144
#define XBF_SHORTS ((size_t)Bn*HW*RECS)
#define XBF_BYTES  (XBF_SHORTS*2)          // 9,437,184
#define WBLOCKS 144        // 36864 weights / 256

typedef __attribute__((ext_vector_type(8))) short  short8;   // 8 bf16 = 4 VGPR
typedef __attribute__((ext_vector_type(4))) short  short4v;  // 8 B
typedef __attribute__((ext_vector_type(4))) float  float4v;  // MFMA acc

__device__ __forceinline__ short f2bf(float f) {
    unsigned u = __builtin_bit_cast(unsigned, f);
    u += 0x7FFFu + ((u >> 16) & 1u);          // RNE (inputs finite)
    return (short)(u >> 16);
}
__device__ __forceinline__ float bf2f(short s) {
    return __builtin_bit_cast(float, ((unsigned)(unsigned short)s) << 16);
}

// ---- Pre-pass (fused): x NCHW f32 -> HWC bf16, and weight -> bf16 K-permuted ----
__global__ __launch_bounds__(NT)
void prep_all(const float* __restrict__ x, short* __restrict__ xbf,
              const float* __restrict__ w, short* __restrict__ wperm) {
    const int blk = blockIdx.x;
    if (blk >= Bn * BLKS_PER_IMG) {
        // weight: wperm[cout*576 + kk*64 + c] = bf16(w[cout*576 + c*9 + kk])
        int i = (blk - Bn * BLKS_PER_IMG) * NT + threadIdx.x;
        if (i < COUTn * KDIM) {
            int cout = i / KDIM;
            int rem  = i - cout * KDIM;
            int kk = rem >> 6;
            int c  = rem & 63;
            wperm[i] = f2bf(w[cout * KDIM + c * K2 + kk]);
        }
        return;
    }
    __shared__ float tile[Cn * 65];     // 16.6 KB
    const int t    = threadIdx.x;
    const int lane = t & 63, wv = t >> 6;
    const int b    = blk & 7;
    const int pix0 = (blk >> 3) * BLK_PIX;

    #pragma unroll
    for (int i = 0; i < 16; ++i) {
        int c = wv + i * 4;
        tile[c * 65 + lane] = x[((size_t)b * Cn + c) * HW + pix0 + lane];
    }
    __syncthreads();
    #pragma unroll
    for (int pass = 0; pass < 4; ++pass) {
        int px = wv * 16 + pass * 4 + (lane >> 4);
        int c4 = (lane & 15) * 4;
        short4v v;
        v[0] = f2bf(tile[(c4 + 0) * 65 + px]);
        v[1] = f2bf(tile[(c4 + 1) * 65 + px]);
        v[2] = f2bf(tile[(c4 + 2) * 65 + px]);
        v[3] = f2bf(tile[(c4 + 3) * 65 + px]);
        *(short4v*)&xbf[((size_t)b * HW + pix0 + px) * RECS + c4] = v;
    }
}

// ---- Main kernel: bf16 HWC gathers (8 x 16B per kk per lane) ----
__global__ __launch_bounds__(NT, 4)
void deform_conv_hwc16(const short* __restrict__ xbf,
                       const float* __restrict__ offset,
                       const short* __restrict__ wperm,
                       float* __restrict__ out) {
    __shared__ int    sA[K2 * BLK_PIX];   // 2.25 KB
    __shared__ float4 sW[K2 * BLK_PIX];   // 9 KB
    __shared__ float  sC[COUTn * 68];     // 17.4 KB epilogue staging

    const int tid  = threadIdx.x;
    const int b    = blockIdx.x & 7;                 // XCD swizzle
    const int pix0 = (blockIdx.x >> 3) * BLK_PIX;

    const short* xb   = xbf + (size_t)b * (HW * RECS);
    const float* offb = offset + (size_t)b * (2 * K2 * HW);

    // ---- Phase 0: sampling metadata per (kk, pixel) ----
    for (int e = tid; e < K2 * BLK_PIX; e += NT) {
        int kk = e >> 6;
        int pl = e & 63;
        int pix = pix0 + pl;
        int h = pix / 96, w = pix - h * 96;
        float offy = offb[(2 * kk) * HW + pix];
        float offx = offb[(2 * kk + 1) * HW + pix];
        float py = (float)(h - 1 + kk / 3) + offy;
        float px = (float)(w - 1 + kk % 3) + offx;
        float y0f = floorf(py), x0f = floorf(px);
        float ly = py - y0f, lx = px - x0f;
        int y0 = (int)y0f, x0 = (int)x0f;
        float vy0 = ((unsigned)y0 < 96u) ? 1.f : 0.f;
        float vy1 = ((unsigned)(y0 + 1) < 96u) ? 1.f : 0.f;
        float vx0 = ((unsigned)x0 < 96u) ? 1.f : 0.f;
        float vx1 = ((unsigned)(x0 + 1) < 96u) ? 1.f : 0.f;
        float w00 = (1.f - ly) * (1.f - lx) * vy0 * vx0;
        float w01 = (1.f - ly) * lx         * vy0 * vx1;
        float w10 = ly * (1.f - lx)         * vy1 * vx0;
        float w11 = ly * lx                 * vy1 * vx1;
        int y0c = min(max(y0, 0), 95);
        int x0c = min(max(x0, 0), 95);
        int dx = min(max(x0 + 1, 0), 95) - x0c;   // 0 or 1
        int dy = min(max(y0 + 1, 0), 95) - y0c;   // 0 or 1
        sA[e] = (y0c * 96 + x0c) | (dx << 14) | (dy << 15);
        sW[e] = make_float4(w00, w01, w10, w11);
    }
    __syncthreads();

    const int lane = tid & 63;
    const int wv   = tid >> 6;
    const int q    = lane >> 4;          // quad 0..3
    const int r    = lane & 15;          // 0..15
    const int plw  = wv * 16 + r;        // B-column pixel (local)

    float4v acc0 = {0.f,0.f,0.f,0.f};
    float4v acc1 = {0.f,0.f,0.f,0.f};
    float4v acc2 = {0.f,0.f,0.f,0.f};
    float4v acc3 = {0.f,0.f,0.f,0.f};

    const short* wbase = wperm + (size_t)r * KDIM + q * 8;

    for (int kk = 0; kk < 9; ++kk) {
        const int idx = kk * BLK_PIX + plw;
        const int pack  = sA[idx];
        const float4 w4 = sW[idx];
        const int a00p = pack & 16383;
        const int dxs  = ((pack >> 14) & 1) * RECS;   // +1 col
        const int dys  = ((pack >> 15) & 1) * ROWS;   // +1 row
        const short* base = xb + (size_t)a00p * RECS + q * 8;

        // Issue all 8 corner loads (both ch-halves) before consuming.
        short8 s00a = *(const short8*)(base);
        short8 s01a = *(const short8*)(base + dxs);
        short8 s10a = *(const short8*)(base + dys);
        short8 s11a = *(const short8*)(base + dys + dxs);
        short8 s00b = *(const short8*)(base + 32);
        short8 s01b = *(const short8*)(base + 32 + dxs);
        short8 s10b = *(const short8*)(base + 32 + dys);
        short8 s11b = *(const short8*)(base + 32 + dys + dxs);

        #pragma unroll
        for (int ch = 0; ch < 2; ++ch) {
            short8 c00 = ch ? s00b : s00a;
            short8 c01 = ch ? s01b : s01a;
            short8 c10 = ch ? s10b : s10a;
            short8 c11 = ch ? s11b : s11a;
            short8 bq;
            #pragma unroll
            for (int j = 0; j < 8; ++j) {
                float v = fmaf(w4.x, bf2f(c00[j]),
                          fmaf(w4.y, bf2f(c01[j]),
                          fmaf(w4.z, bf2f(c10[j]),
                               w4.w * bf2f(c11[j]))));
                bq[j] = f2bf(v);
            }
            const short* wp = wbase + kk * 64 + ch * 32;
            short8 a0 = *(const short8*)(wp + 0 * 16 * KDIM);
            short8 a1 = *(const short8*)(wp + 1 * 16 * KDIM);
            short8 a2 = *(const short8*)(wp + 2 * 16 * KDIM);
            short8 a3 = *(const short8*)(wp + 3 * 16 * KDIM);
            acc0 = __builtin_amdgcn_mfma_f32_16x16x32_bf16(a0, bq, acc0, 0, 0, 0);
            acc1 = __builtin_amdgcn_mfma_f32_16x16x32_bf16(a1, bq, acc1, 0, 0, 0);
            acc2 = __builtin_amdgcn_mfma_f32_16x16x32_bf16(a2, bq, acc2, 0, 0, 0);
            acc3 = __builtin_amdgcn_mfma_f32_16x16x32_bf16(a3, bq, acc3, 0, 0, 0);
        }
    }

    // ---- Epilogue: stage through LDS for full-line stores ----
    #pragma unroll
    for (int mt = 0; mt < 4; ++mt) {
        float4v a = (mt == 0) ? acc0 : (mt == 1) ? acc1 : (mt == 2) ? acc2 : acc3;
        int cout = mt * 16 + q * 4;
        #pragma unroll
        for (int reg = 0; reg < 4; ++reg)
            sC[(cout + reg) * 68 + plw] = a[reg];
    }
    __syncthreads();

    #pragma unroll
    for (int i = 0; i < 4; ++i) {
        int cout = (tid >> 4) + i * 16;
        int px4  = (tid & 15) * 4;
        float4 v = *(const float4*)&sC[cout * 68 + px4];
        *(float4*)&out[((size_t)(b * COUTn + cout)) * HW + pix0 + px4] = v;
    }
}

// ---- Fallback (round-2 structure, NCHW gathers) if ws too small ----
__global__ void convert_weight(const float* __restrict__ w, short* __restrict__ wbf) {
    int i = blockIdx.x * 256 + threadIdx.x;
    if (i < COUTn * KDIM) wbf[i] = f2bf(w[i]);
}

__global__ __launch_bounds__(NT, 4)
void deform_conv_nchw(const float* __restrict__ x,
                      const float* __restrict__ offset,
                      const short* __restrict__ wbf,
                      float* __restrict__ out) {
    __shared__ int    sA[K2 * BLK_PIX];
    __shared__ float4 sW[K2 * BLK_PIX];

    const int tid  = threadIdx.x;
    const int b    = blockIdx.x / BLKS_PER_IMG;
    const int pix0 = (blockIdx.x - b * BLKS_PER_IMG) * BLK_PIX;

    const float* xb   = x + (size_t)b * (Cn * HW);
    const float* offb = offset + (size_t)b * (2 * K2 * HW);

    for (int e = tid; e < K2 * BLK_PIX; e += NT) {
        int kk = e >> 6;
        int pl = e & 63;
        int pix = pix0 + pl;
        int h = pix / 96, w = pix - h * 96;
        float offy = offb[(2 * kk) * HW + pix];
        float offx = offb[(2 * kk + 1) * HW + pix];
        float py = (float)(h - 1 + kk / 3) + offy;
        float px = (float)(w - 1 + kk % 3) + offx;
        float y0f = floorf(py), x0f = floorf(px);
        float ly = py - y0f, lx = px - x0f;
        int y0 = (int)y0f, x0 = (int)x0f;
        float vy0 = ((unsigned)y0 < 96u) ? 1.f : 0.f;
        float vy1 = ((unsigned)(y0 + 1) < 96u) ? 1.f : 0.f;
        float vx0 = ((unsigned)x0 < 96u) ? 1.f : 0.f;
        float vx1 = ((unsigned)(x0 + 1) < 96u) ? 1.f : 0.f;
        float w00 = (1.f - ly) * (1.f - lx) * vy0 * vx0;
        float w01 = (1.f - ly) * lx         * vy0 * vx1;
        float w10 = ly * (1.f - lx)         * vy1 * vx0;
        float w11 = ly * lx                 * vy1 * vx1;
        int y0c = min(max(y0, 0), 95);
        int x0c = min(max(x0, 0), 95);
        int dx = min(max(x0 + 1, 0), 95) - x0c;
        int dy = min(max(y0 + 1, 0), 95) - y0c;
        sA[e] = (y0c * 96 + x0c) | (dx << 14) | (dy << 15);
        sW[e] = make_float4(w00, w01, w10, w11);
    }
    __syncthreads();

    const int lane = tid & 63;
    const int wv   = tid >> 6;
    const int q    = lane >> 4;
    const int r    = lane & 15;
    const int plw  = wv * 16 + r;

    float4v acc0 = {0.f,0.f,0.f,0.f};
    float4v acc1 = {0.f,0.f,0.f,0.f};
    float4v acc2 = {0.f,0.f,0.f,0.f};
    float4v acc3 = {0.f,0.f,0.f,0.f};

    for (int ks = 0; ks < 18; ++ks) {
        const int kb = ks * 32;
        const short* wp = wbf + (size_t)r * KDIM + kb + q * 8;
        short8 a0 = *(const short8*)(wp + 0 * 16 * KDIM);
        short8 a1 = *(const short8*)(wp + 1 * 16 * KDIM);
        short8 a2 = *(const short8*)(wp + 2 * 16 * KDIM);
        short8 a3 = *(const short8*)(wp + 3 * 16 * KDIM);

        short8 bq;
        #pragma unroll
        for (int j = 0; j < 8; ++j) {
            unsigned kg = (unsigned)(kb + q * 8 + j);
            unsigned c  = kg / 9u;
            unsigned kk = kg - c * 9u;
            int idx = (int)kk * BLK_PIX + plw;
            int pack  = sA[idx];
            float4 w4 = sW[idx];
            int a00  = pack & 16383;
            int dxv  = (pack >> 14) & 1;
            int dy96 = ((pack >> 15) & 1) * 96;
            const float* xc = xb + (size_t)c * HW;
            float v = w4.x * xc[a00]
                    + w4.y * xc[a00 + dxv]
                    + w4.z * xc[a00 + dy96]
                    + w4.w * xc[a00 + dy96 + dxv];
            bq[j] = f2bf(v);
        }
        acc0 = __builtin_amdgcn_mfma_f32_16x16x32_bf16(a0, bq, acc0, 0, 0, 0);
        acc1 = __builtin_amdgcn_mfma_f32_16x16x32_bf16(a1, bq, acc1, 0, 0, 0);
        acc2 = __builtin_amdgcn_mfma_f32_16x16x32_bf16(a2, bq, acc2, 0, 0, 0);
        acc3 = __builtin_amdgcn_mfma_f32_16x16x32_bf16(a3, bq, acc3, 0, 0, 0);
    }

    float* ob = out + (size_t)b * COUTn * HW + pix0 + plw;
    #pragma unroll
    for (int mt = 0; mt < 4; ++mt) {
        float4v a = (mt == 0) ? acc0 : (mt == 1) ? acc1 : (mt == 2) ? acc2 : acc3;
        float* p = ob + (size_t)(mt * 16 + q * 4) * HW;
        p[0 * HW] = a[0];
        p[1 * HW] = a[1];
        p[2 * HW] = a[2];
        p[3 * HW] = a[3];
    }
}

extern "C" void kernel_launch(void* const* d_in, const int* in_sizes, int n_in,
                              void* d_out, int out_size, void* d_ws, size_t ws_size,
                              hipStream_t stream) {
    const float* x      = (const float*)d_in[0];
    const float* offset = (const float*)d_in[1];
    const float* weight = (const float*)d_in[2];
    float* out = (float*)d_out;

    const size_t need = XBF_BYTES + (size_t)COUTn * KDIM * 2;
    if (ws_size >= need) {
        short* xbf   = (short*)d_ws;
        short* wperm = (short*)((char*)d_ws + XBF_BYTES);
        prep_all<<<dim3(Bn * BLKS_PER_IMG + WBLOCKS), dim3(NT), 0, stream>>>(x, xbf, weight, wperm);
        deform_conv_hwc16<<<dim3(Bn * BLKS_PER_IMG), dim3(NT), 0, stream>>>(xbf, offset, wperm, out);
    } else {
        short* wbf = (short*)d_ws;   // 73,728 B
        convert_weight<<<dim3((COUTn * KDIM + 255) / 256), dim3(256), 0, stream>>>(weight, wbf);
        deform_conv_nchw<<<dim3(Bn * BLKS_PER_IMG), dim3(NT), 0, stream>>>(x, offset, wbf, out);
    }
}

// Round 6
// 117.769 us; speedup vs baseline: 2.1220x; 1.3333x over previous
//
#include <hip/hip_runtime.h>

// Problem constants
#define Bn     8
#define Cn     64
#define Hn     96
#define Wn     96
#define HW     9216        // Hn*Wn
#define K2     9
#define COUTn  64
#define KDIM   576         // Cn*K2
#define NT     256
#define RECS   64          // shorts per HWC bf16 pixel record (128 B)
#define ROWS   (Wn*RECS)   // shorts per image row = 6144
#define XBF_SHORTS ((size_t)Bn*HW*RECS)
#define XBF_BYTES  (XBF_SHORTS*2)          // 9,437,184
// Tile geometry: 32 wide x 2 tall = 64 pixels/block
#define TW     32
#define TH     2
#define TILES_X 3
#define BLKS_PER_IMG 144   // (96/32)*(96/2)
#define BLK_PIX 64
// LDS window: 40 cols x 10 rows of 128B records, padded to 144B stride
#define WW     40
#define WH     10
#define WSTR   144                 // bytes per record in LDS (pad 16)
#define WDY    (WW*WSTR)           // 5760 = +1 row step
#define WIN_BYTES (WW*WH*WSTR)     // 57600
#define WCHUNKS (WW*WH*8)          // 3200 16B-chunks to stage

typedef __attribute__((ext_vector_type(8))) short  short8;   // 8 bf16 = 4 VGPR
typedef __attribute__((ext_vector_type(4))) short  short4v;  // 8 B
typedef __attribute__((ext_vector_type(4))) float  float4v;  // MFMA acc

__device__ __forceinline__ short f2bf(float f) {
    unsigned u = __builtin_bit_cast(unsigned, f);
    u += 0x7FFFu + ((u >> 16) & 1u);          // RNE (inputs finite)
    return (short)(u >> 16);
}
__device__ __forceinline__ float bf2f(short s) {
    return __builtin_bit_cast(float, ((unsigned)(unsigned short)s) << 16);
}

// ---- Pre-pass (fused): x NCHW f32 -> HWC bf16, weight -> bf16 fragment-major ----
// wfrag layout: [mt(4)][kk(9)][ch(2)][lane(64)][j(8)] so an A-fragment wave-load
// is 1024B contiguous. element: m=lane&15, q=lane>>4; cout=mt*16+m; c=ch*32+q*8+j.
__global__ __launch_bounds__(NT)
void prep_all(const float* __restrict__ x, short* __restrict__ xbf,
              const float* __restrict__ w, short* __restrict__ wfrag) {
    const int blk = blockIdx.x;
    if (blk >= Bn * BLKS_PER_IMG) {
        int i = (blk - Bn * BLKS_PER_IMG) * NT + threadIdx.x;
        if (i < COUTn * KDIM) {
            int j    = i & 7;
            int lane = (i >> 3) & 63;
            int ch   = (i >> 9) & 1;
            int mk   = i >> 10;          // mt*9 + kk
            int kk   = mk % 9;
            int mt   = mk / 9;
            int m = lane & 15, q = lane >> 4;
            int cout = mt * 16 + m;
            int c    = ch * 32 + q * 8 + j;
            wfrag[i] = f2bf(w[cout * KDIM + c * K2 + kk]);
        }
        return;
    }
    __shared__ float tile[Cn * 65];     // 16.6 KB
    const int t    = threadIdx.x;
    const int lane = t & 63, wv = t >> 6;
    const int b    = blk & 7;
    const int tl   = blk >> 3;
    // linear 64-pixel groups for the transpose (layout-agnostic)
    const int pix0 = tl * BLK_PIX;

    #pragma unroll
    for (int i = 0; i < 16; ++i) {
        int c = wv + i * 4;
        tile[c * 65 + lane] = x[((size_t)b * Cn + c) * HW + pix0 + lane];
    }
    __syncthreads();
    #pragma unroll
    for (int pass = 0; pass < 4; ++pass) {
        int px = wv * 16 + pass * 4 + (lane >> 4);
        int c4 = (lane & 15) * 4;
        short4v v;
        v[0] = f2bf(tile[(c4 + 0) * 65 + px]);
        v[1] = f2bf(tile[(c4 + 1) * 65 + px]);
        v[2] = f2bf(tile[(c4 + 2) * 65 + px]);
        v[3] = f2bf(tile[(c4 + 3) * 65 + px]);
        *(short4v*)&xbf[((size_t)b * HW + pix0 + px) * RECS + c4] = v;
    }
}

// ---- Main kernel: LDS-staged window, all gathers from LDS ----
__global__ __launch_bounds__(NT, 2)
void deform_conv_lds(const short* __restrict__ xbf,
                     const float* __restrict__ offset,
                     const short* __restrict__ wfrag,
                     float* __restrict__ out) {
    __shared__ __align__(16) char smem[WIN_BYTES];   // 57.6 KB window; epilogue sC aliases
    __shared__ int    sA [K2 * BLK_PIX];   // 2.25 KB: LDS off | dx | dy | ok
    __shared__ int    sA2[K2 * BLK_PIX];   // 2.25 KB: global pack (fallback)
    __shared__ float4 sW [K2 * BLK_PIX];   // 9 KB bilinear weights

    const int tid  = threadIdx.x;
    const int b    = blockIdx.x & 7;                 // XCD swizzle
    const int tl   = blockIdx.x >> 3;
    const int ty0  = (tl / TILES_X) * TH;
    const int tx0  = (tl % TILES_X) * TW;
    const int wy0  = min(max(ty0 - 4, 0), Hn - WH);  // window origin (in-image)
    const int wx0  = min(max(tx0 - 4, 0), Wn - WW);

    const short* xb   = xbf + (size_t)b * (HW * RECS);
    const float* offb = offset + (size_t)b * (2 * K2 * HW);

    // ---- Phase 0a: sampling metadata per (kk, pixel) ----
    for (int e = tid; e < K2 * BLK_PIX; e += NT) {
        int kk = e >> 6;
        int pl = e & 63;
        int h = ty0 + (pl >> 5);
        int w = tx0 + (pl & 31);
        int pix = h * 96 + w;
        float offy = offb[(2 * kk) * HW + pix];
        float offx = offb[(2 * kk + 1) * HW + pix];
        float py = (float)(h - 1 + kk / 3) + offy;
        float px = (float)(w - 1 + kk % 3) + offx;
        float y0f = floorf(py), x0f = floorf(px);
        float ly = py - y0f, lx = px - x0f;
        int y0 = (int)y0f, x0 = (int)x0f;
        float vy0 = ((unsigned)y0 < 96u) ? 1.f : 0.f;
        float vy1 = ((unsigned)(y0 + 1) < 96u) ? 1.f : 0.f;
        float vx0 = ((unsigned)x0 < 96u) ? 1.f : 0.f;
        float vx1 = ((unsigned)(x0 + 1) < 96u) ? 1.f : 0.f;
        float w00 = (1.f - ly) * (1.f - lx) * vy0 * vx0;
        float w01 = (1.f - ly) * lx         * vy0 * vx1;
        float w10 = ly * (1.f - lx)         * vy1 * vx0;
        float w11 = ly * lx                 * vy1 * vx1;
        int y0c = min(max(y0, 0), 95);
        int x0c = min(max(x0, 0), 95);
        int dx = min(max(x0 + 1, 0), 95) - x0c;   // 0 or 1
        int dy = min(max(y0 + 1, 0), 95) - y0c;   // 0 or 1
        int ok = (y0c >= wy0) & (y0c + dy <= wy0 + WH - 1) &
                 (x0c >= wx0) & (x0c + dx <= wx0 + WW - 1);
        int woff = ok ? ((y0c - wy0) * WW + (x0c - wx0)) * WSTR : 0;
        sA [e] = woff | (dx << 16) | (dy << 17) | (ok << 18);
        sA2[e] = (y0c * 96 + x0c) | (dx << 14) | (dy << 15);
        sW [e] = make_float4(w00, w01, w10, w11);
    }

    // ---- Phase 0b: stage the 40x10 record window into LDS (dense) ----
    {
        const size_t rowbase = (size_t)(wy0 * 96 + wx0) * RECS;   // shorts
        #pragma unroll 4
        for (int i = 0; i < 13; ++i) {
            int c = i * NT + tid;
            if (c < WCHUNKS) {
                int rec = c >> 3;
                int within = (c & 7) * 16;          // bytes
                int row = rec / WW;
                int col = rec - row * WW;
                const char* g = (const char*)(xb + rowbase + ((size_t)row * 96 + col) * RECS) + within;
                *(short8*)(smem + rec * WSTR + within) = *(const short8*)g;
            }
        }
    }
    __syncthreads();

    const int lane = tid & 63;
    const int wv   = tid >> 6;
    const int q    = lane >> 4;          // quad 0..3
    const int r    = lane & 15;          // 0..15
    const int plw  = wv * 16 + r;        // B-column pixel (local)

    float4v acc0 = {0.f,0.f,0.f,0.f};
    float4v acc1 = {0.f,0.f,0.f,0.f};
    float4v acc2 = {0.f,0.f,0.f,0.f};
    float4v acc3 = {0.f,0.f,0.f,0.f};

    const short* wlane = wfrag + lane * 8;

    for (int kk = 0; kk < 9; ++kk) {
        const int idx = kk * BLK_PIX + plw;
        const int pk    = sA[idx];
        const float4 w4 = sW[idx];

        short8 s00a, s01a, s10a, s11a, s00b, s01b, s10b, s11b;
        if (pk & (1 << 18)) {
            // LDS window path (always taken for this data)
            const char* base = smem + (pk & 0xFFFF) + q * 16;
            const int dxs = ((pk >> 16) & 1) * WSTR;
            const int dys = ((pk >> 17) & 1) * WDY;
            s00a = *(const short8*)(base);
            s01a = *(const short8*)(base + dxs);
            s10a = *(const short8*)(base + dys);
            s11a = *(const short8*)(base + dys + dxs);
            s00b = *(const short8*)(base + 64);
            s01b = *(const short8*)(base + 64 + dxs);
            s10b = *(const short8*)(base + 64 + dys);
            s11b = *(const short8*)(base + 64 + dys + dxs);
        } else {
            // Global fallback (pathological offsets only)
            const int pk2  = sA2[idx];
            const int a00p = pk2 & 16383;
            const int dxs  = ((pk2 >> 14) & 1) * RECS;
            const int dys  = ((pk2 >> 15) & 1) * ROWS;
            const short* base = xb + (size_t)a00p * RECS + q * 8;
            s00a = *(const short8*)(base);
            s01a = *(const short8*)(base + dxs);
            s10a = *(const short8*)(base + dys);
            s11a = *(const short8*)(base + dys + dxs);
            s00b = *(const short8*)(base + 32);
            s01b = *(const short8*)(base + 32 + dxs);
            s10b = *(const short8*)(base + 32 + dys);
            s11b = *(const short8*)(base + 32 + dys + dxs);
        }

        #pragma unroll
        for (int ch = 0; ch < 2; ++ch) {
            short8 c00 = ch ? s00b : s00a;
            short8 c01 = ch ? s01b : s01a;
            short8 c10 = ch ? s10b : s10a;
            short8 c11 = ch ? s11b : s11a;
            short8 bq;
            #pragma unroll
            for (int j = 0; j < 8; ++j) {
                float v = fmaf(w4.x, bf2f(c00[j]),
                          fmaf(w4.y, bf2f(c01[j]),
                          fmaf(w4.z, bf2f(c10[j]),
                               w4.w * bf2f(c11[j]))));
                bq[j] = f2bf(v);
            }
            // A fragments: dense 1024B wave-loads from fragment-major wfrag
            const short* wkc = wlane + (size_t)(kk * 2 + ch) * 512;
            short8 a0 = *(const short8*)(wkc + 0 * 9216);
            short8 a1 = *(const short8*)(wkc + 1 * 9216);
            short8 a2 = *(const short8*)(wkc + 2 * 9216);
            short8 a3 = *(const short8*)(wkc + 3 * 9216);
            acc0 = __builtin_amdgcn_mfma_f32_16x16x32_bf16(a0, bq, acc0, 0, 0, 0);
            acc1 = __builtin_amdgcn_mfma_f32_16x16x32_bf16(a1, bq, acc1, 0, 0, 0);
            acc2 = __builtin_amdgcn_mfma_f32_16x16x32_bf16(a2, bq, acc2, 0, 0, 0);
            acc3 = __builtin_amdgcn_mfma_f32_16x16x32_bf16(a3, bq, acc3, 0, 0, 0);
        }
    }

    // ---- Epilogue: stage through LDS (aliases window) for dense stores ----
    __syncthreads();                       // window reads done; reuse smem
    float* sC = (float*)smem;              // [64][66] floats = 16.9 KB
    #pragma unroll
    for (int mt = 0; mt < 4; ++mt) {
        float4v a = (mt == 0) ? acc0 : (mt == 1) ? acc1 : (mt == 2) ? acc2 : acc3;
        int cout = mt * 16 + q * 4;
        #pragma unroll
        for (int reg = 0; reg < 4; ++reg)
            sC[(cout + reg) * 66 + plw] = a[reg];
    }
    __syncthreads();

    #pragma unroll
    for (int i = 0; i < 4; ++i) {
        int idx  = i * NT + tid;
        int cout = idx >> 4;
        int px4  = (idx & 15) * 4;
        int row  = px4 >> 5;
        int col  = px4 & 31;
        float4 v = *(const float4*)&sC[cout * 66 + px4];
        *(float4*)&out[((size_t)(b * COUTn + cout)) * HW + (ty0 + row) * 96 + tx0 + col] = v;
    }
}

// ---- Fallback (round-2 structure, NCHW gathers) if ws too small ----
__global__ void convert_weight(const float* __restrict__ w, short* __restrict__ wbf) {
    int i = blockIdx.x * 256 + threadIdx.x;
    if (i < COUTn * KDIM) wbf[i] = f2bf(w[i]);
}

__global__ __launch_bounds__(NT, 4)
void deform_conv_nchw(const float* __restrict__ x,
                      const float* __restrict__ offset,
                      const short* __restrict__ wbf,
                      float* __restrict__ out) {
    __shared__ int    sA[K2 * BLK_PIX];
    __shared__ float4 sW[K2 * BLK_PIX];

    const int tid  = threadIdx.x;
    const int b    = blockIdx.x / BLKS_PER_IMG;
    const int pix0 = (blockIdx.x - b * BLKS_PER_IMG) * BLK_PIX;

    const float* xb   = x + (size_t)b * (Cn * HW);
    const float* offb = offset + (size_t)b * (2 * K2 * HW);

    for (int e = tid; e < K2 * BLK_PIX; e += NT) {
        int kk = e >> 6;
        int pl = e & 63;
        int pix = pix0 + pl;
        int h = pix / 96, w = pix - h * 96;
        float offy = offb[(2 * kk) * HW + pix];
        float offx = offb[(2 * kk + 1) * HW + pix];
        float py = (float)(h - 1 + kk / 3) + offy;
        float px = (float)(w - 1 + kk % 3) + offx;
        float y0f = floorf(py), x0f = floorf(px);
        float ly = py - y0f, lx = px - x0f;
        int y0 = (int)y0f, x0 = (int)x0f;
        float vy0 = ((unsigned)y0 < 96u) ? 1.f : 0.f;
        float vy1 = ((unsigned)(y0 + 1) < 96u) ? 1.f : 0.f;
        float vx0 = ((unsigned)x0 < 96u) ? 1.f : 0.f;
        float vx1 = ((unsigned)(x0 + 1) < 96u) ? 1.f : 0.f;
        float w00 = (1.f - ly) * (1.f - lx) * vy0 * vx0;
        float w01 = (1.f - ly) * lx         * vy0 * vx1;
        float w10 = ly * (1.f - lx)         * vy1 * vx0;
        float w11 = ly * lx                 * vy1 * vx1;
        int y0c = min(max(y0, 0), 95);
        int x0c = min(max(x0, 0), 95);
        int dx = min(max(x0 + 1, 0), 95) - x0c;
        int dy = min(max(y0 + 1, 0), 95) - y0c;
        sA[e] = (y0c * 96 + x0c) | (dx << 14) | (dy << 15);
        sW[e] = make_float4(w00, w01, w10, w11);
    }
    __syncthreads();

    const int lane = tid & 63;
    const int wv   = tid >> 6;
    const int q    = lane >> 4;
    const int r    = lane & 15;
    const int plw  = wv * 16 + r;

    float4v acc0 = {0.f,0.f,0.f,0.f};
    float4v acc1 = {0.f,0.f,0.f,0.f};
    float4v acc2 = {0.f,0.f,0.f,0.f};
    float4v acc3 = {0.f,0.f,0.f,0.f};

    for (int ks = 0; ks < 18; ++ks) {
        const int kb = ks * 32;
        const short* wp = wbf + (size_t)r * KDIM + kb + q * 8;
        short8 a0 = *(const short8*)(wp + 0 * 16 * KDIM);
        short8 a1 = *(const short8*)(wp + 1 * 16 * KDIM);
        short8 a2 = *(const short8*)(wp + 2 * 16 * KDIM);
        short8 a3 = *(const short8*)(wp + 3 * 16 * KDIM);

        short8 bq;
        #pragma unroll
        for (int j = 0; j < 8; ++j) {
            unsigned kg = (unsigned)(kb + q * 8 + j);
            unsigned c  = kg / 9u;
            unsigned kk = kg - c * 9u;
            int idx = (int)kk * BLK_PIX + plw;
            int pack  = sA[idx];
            float4 w4 = sW[idx];
            int a00  = pack & 16383;
            int dxv  = (pack >> 14) & 1;
            int dy96 = ((pack >> 15) & 1) * 96;
            const float* xc = xb + (size_t)c * HW;
            float v = w4.x * xc[a00]
                    + w4.y * xc[a00 + dxv]
                    + w4.z * xc[a00 + dy96]
                    + w4.w * xc[a00 + dy96 + dxv];
            bq[j] = f2bf(v);
        }
        acc0 = __builtin_amdgcn_mfma_f32_16x16x32_bf16(a0, bq, acc0, 0, 0, 0);
        acc1 = __builtin_amdgcn_mfma_f32_16x16x32_bf16(a1, bq, acc1, 0, 0, 0);
        acc2 = __builtin_amdgcn_mfma_f32_16x16x32_bf16(a2, bq, acc2, 0, 0, 0);
        acc3 = __builtin_amdgcn_mfma_f32_16x16x32_bf16(a3, bq, acc3, 0, 0, 0);
    }

    float* ob = out + (size_t)b * COUTn * HW + pix0 + plw;
    #pragma unroll
    for (int mt = 0; mt < 4; ++mt) {
        float4v a = (mt == 0) ? acc0 : (mt == 1) ? acc1 : (mt == 2) ? acc2 : acc3;
        float* p = ob + (size_t)(mt * 16 + q * 4) * HW;
        p[0 * HW] = a[0];
        p[1 * HW] = a[1];
        p[2 * HW] = a[2];
        p[3 * HW] = a[3];
    }
}

extern "C" void kernel_launch(void* const* d_in, const int* in_sizes, int n_in,
                              void* d_out, int out_size, void* d_ws, size_t ws_size,
                              hipStream_t stream) {
    const float* x      = (const float*)d_in[0];
    const float* offset = (const float*)d_in[1];
    const float* weight = (const float*)d_in[2];
    float* out = (float*)d_out;

    const size_t need = XBF_BYTES + (size_t)COUTn * KDIM * 2;
    if (ws_size >= need) {
        short* xbf   = (short*)d_ws;
        short* wfrag = (short*)((char*)d_ws + XBF_BYTES);
        prep_all<<<dim3(Bn * BLKS_PER_IMG + 144), dim3(NT), 0, stream>>>(x, xbf, weight, wfrag);
        deform_conv_lds<<<dim3(Bn * BLKS_PER_IMG), dim3(NT), 0, stream>>>(xbf, offset, wfrag, out);
    } else {
        short* wbf = (short*)d_ws;   // 73,728 B
        convert_weight<<<dim3((COUTn * KDIM + 255) / 256), dim3(256), 0, stream>>>(weight, wbf);
        deform_conv_nchw<<<dim3(Bn * BLKS_PER_IMG), dim3(NT), 0, stream>>>(x, offset, wbf, out);
    }
}

// Round 7
// 109.919 us; speedup vs baseline: 2.2736x; 1.0714x over previous
//
#include <hip/hip_runtime.h>

// Problem constants
#define Bn     8
#define Cn     64
#define Hn     96
#define Wn     96
#define HW     9216        // Hn*Wn
#define K2     9
#define COUTn  64
#define KDIM   576         // Cn*K2
#define NT     256
// Tile geometry: 16 wide x 4 tall = 64 pixels/block
#define TW     16
#define TH     4
#define TILES_X 6
#define BLKS_PER_IMG 144   // (96/16)*(96/4)
#define BLK_PIX 64
// LDS window: 24 cols x 12 rows of 128B bf16 records, padded to 144B stride
#define WW     24
#define WH     12
#define WSTR   144                 // bytes per record in LDS (pad 16)
#define WDY    (WW*WSTR)           // 3456 = +1 row step
#define WIN_BYTES (WW*WH*WSTR)     // 41472

typedef __attribute__((ext_vector_type(8))) short    short8;   // 8 bf16 = 4 VGPR
typedef __attribute__((ext_vector_type(4))) float    float4v;  // MFMA acc
typedef __attribute__((ext_vector_type(4))) _Float16 half4v;   // 8 B

__device__ __forceinline__ short f2bf(float f) {
    unsigned u = __builtin_bit_cast(unsigned, f);
    u += 0x7FFFu + ((u >> 16) & 1u);          // RNE (inputs finite)
    return (short)(u >> 16);
}
__device__ __forceinline__ float bf2f(short s) {
    return __builtin_bit_cast(float, ((unsigned)(unsigned short)s) << 16);
}

// ---- Pre-pass: weight -> bf16 fragment-major ----
// wfrag layout: [mt(4)][kk(9)][ch(2)][lane(64)][j(8)]: A-fragment wave-load is
// 1024B contiguous. element: m=lane&15, q=lane>>4; cout=mt*16+m; c=ch*32+q*8+j.
__global__ void prep_weight(const float* __restrict__ w, short* __restrict__ wfrag) {
    int i = blockIdx.x * NT + threadIdx.x;
    if (i < COUTn * KDIM) {
        int j    = i & 7;
        int lane = (i >> 3) & 63;
        int ch   = (i >> 9) & 1;
        int mk   = i >> 10;          // mt*9 + kk
        int kk   = mk % 9;
        int mt   = mk / 9;
        int m = lane & 15, q = lane >> 4;
        int cout = mt * 16 + m;
        int c    = ch * 32 + q * 8 + j;
        wfrag[i] = f2bf(w[cout * KDIM + c * K2 + kk]);
    }
}

// ---- Main kernel: stage NCHW f32 window -> LDS bf16 HWC, gather from LDS ----
__global__ __launch_bounds__(NT, 3)
void deform_conv_win(const float* __restrict__ x,
                     const float* __restrict__ offset,
                     const short* __restrict__ wfrag,
                     float* __restrict__ out) {
    __shared__ __align__(16) char smem[WIN_BYTES];  // 41.5 KB window; epilogue sC aliases
    __shared__ int    sA [K2 * BLK_PIX];   // 2.25 KB: LDS off | dx | dy | ok
    __shared__ int    sA2[K2 * BLK_PIX];   // 2.25 KB: global pack (fallback)
    __shared__ half4v sWh[K2 * BLK_PIX];   // 4.5 KB bilinear weights (fp16)

    const int tid  = threadIdx.x;
    const int b    = blockIdx.x & 7;                 // XCD swizzle
    const int tl   = blockIdx.x >> 3;
    const int ty0  = (tl / TILES_X) * TH;
    const int tx0  = (tl % TILES_X) * TW;
    const int wy0  = min(max(ty0 - 4, 0), Hn - WH);  // window origin (in-image)
    const int wx0  = min(max(tx0 - 4, 0), Wn - WW);

    const float* xb   = x + (size_t)b * (Cn * HW);
    const float* offb = offset + (size_t)b * (2 * K2 * HW);

    const int lane = tid & 63;
    const int wv   = tid >> 6;

    // ---- Phase 0a: sampling metadata per (kk, pixel) ----
    for (int e = tid; e < K2 * BLK_PIX; e += NT) {
        int kk = e >> 6;
        int pl = e & 63;
        int h = ty0 + (pl >> 4);
        int w = tx0 + (pl & 15);
        int pix = h * 96 + w;
        float offy = offb[(2 * kk) * HW + pix];
        float offx = offb[(2 * kk + 1) * HW + pix];
        float py = (float)(h - 1 + kk / 3) + offy;
        float px = (float)(w - 1 + kk % 3) + offx;
        float y0f = floorf(py), x0f = floorf(px);
        float ly = py - y0f, lx = px - x0f;
        int y0 = (int)y0f, x0 = (int)x0f;
        float vy0 = ((unsigned)y0 < 96u) ? 1.f : 0.f;
        float vy1 = ((unsigned)(y0 + 1) < 96u) ? 1.f : 0.f;
        float vx0 = ((unsigned)x0 < 96u) ? 1.f : 0.f;
        float vx1 = ((unsigned)(x0 + 1) < 96u) ? 1.f : 0.f;
        float w00 = (1.f - ly) * (1.f - lx) * vy0 * vx0;
        float w01 = (1.f - ly) * lx         * vy0 * vx1;
        float w10 = ly * (1.f - lx)         * vy1 * vx0;
        float w11 = ly * lx                 * vy1 * vx1;
        int y0c = min(max(y0, 0), 95);
        int x0c = min(max(x0, 0), 95);
        int dx = min(max(x0 + 1, 0), 95) - x0c;   // 0 or 1
        int dy = min(max(y0 + 1, 0), 95) - y0c;   // 0 or 1
        int ok = (y0c >= wy0) & (y0c + dy <= wy0 + WH - 1) &
                 (x0c >= wx0) & (x0c + dx <= wx0 + WW - 1);
        int woff = ok ? ((y0c - wy0) * WW + (x0c - wx0)) * WSTR : 0;
        sA [e] = woff | (dx << 16) | (dy << 17) | (ok << 18);
        sA2[e] = (y0c * 96 + x0c) | (dx << 14) | (dy << 15);
        half4v hv;
        hv[0] = (_Float16)w00; hv[1] = (_Float16)w01;
        hv[2] = (_Float16)w10; hv[3] = (_Float16)w11;
        sWh[e] = hv;
    }

    // ---- Phase 0b: stage 24x12 window from NCHW f32 -> LDS bf16 HWC ----
    // lane = channel (global dwordx4 strided across c-planes, L2-resident);
    // LDS b16 writes are 64-lane contiguous (2 lanes/bank = free).
    {
        const float* xg = xb + (size_t)lane * HW + wy0 * 96 + wx0;
        #pragma unroll
        for (int p2 = 0; p2 < 18; ++p2) {
            int idx2 = p2 * 4 + wv;           // 0..71 = row*6 + colgroup
            int row  = idx2 / 6;
            int c4   = (idx2 - row * 6) * 4;  // col 0,4,8,12,16,20
            float4 v = *(const float4*)(xg + row * 96 + c4);
            char* dst = smem + (row * WW + c4) * WSTR + lane * 2;
            *(short*)(dst + 0 * WSTR) = f2bf(v.x);
            *(short*)(dst + 1 * WSTR) = f2bf(v.y);
            *(short*)(dst + 2 * WSTR) = f2bf(v.z);
            *(short*)(dst + 3 * WSTR) = f2bf(v.w);
        }
    }
    __syncthreads();

    const int q    = lane >> 4;          // quad 0..3
    const int r    = lane & 15;          // 0..15
    const int plw  = wv * 16 + r;        // B-column pixel (local)

    float4v acc0 = {0.f,0.f,0.f,0.f};
    float4v acc1 = {0.f,0.f,0.f,0.f};
    float4v acc2 = {0.f,0.f,0.f,0.f};
    float4v acc3 = {0.f,0.f,0.f,0.f};

    const short* wlane = wfrag + lane * 8;

    for (int kk = 0; kk < 9; ++kk) {
        const int idx = kk * BLK_PIX + plw;
        const int pk  = sA[idx];
        const half4v hv = sWh[idx];
        const float w4x = (float)hv[0], w4y = (float)hv[1];
        const float w4z = (float)hv[2], w4w = (float)hv[3];

        short8 bq0, bq1;
        if (pk & (1 << 18)) {
            // LDS window path (always taken for this data)
            const char* base = smem + (pk & 0xFFFF) + q * 16;
            const int dxs = ((pk >> 16) & 1) * WSTR;
            const int dys = ((pk >> 17) & 1) * WDY;
            short8 s00a = *(const short8*)(base);
            short8 s01a = *(const short8*)(base + dxs);
            short8 s10a = *(const short8*)(base + dys);
            short8 s11a = *(const short8*)(base + dys + dxs);
            short8 s00b = *(const short8*)(base + 64);
            short8 s01b = *(const short8*)(base + 64 + dxs);
            short8 s10b = *(const short8*)(base + 64 + dys);
            short8 s11b = *(const short8*)(base + 64 + dys + dxs);
            #pragma unroll
            for (int j = 0; j < 8; ++j) {
                bq0[j] = f2bf(fmaf(w4x, bf2f(s00a[j]),
                              fmaf(w4y, bf2f(s01a[j]),
                              fmaf(w4z, bf2f(s10a[j]),
                                   w4w * bf2f(s11a[j])))));
                bq1[j] = f2bf(fmaf(w4x, bf2f(s00b[j]),
                              fmaf(w4y, bf2f(s01b[j]),
                              fmaf(w4z, bf2f(s10b[j]),
                                   w4w * bf2f(s11b[j])))));
            }
        } else {
            // Global f32 fallback (pathological offsets only; correct, slow)
            const int pk2  = sA2[idx];
            const int a00p = pk2 & 16383;
            const int dxv  = (pk2 >> 14) & 1;
            const int dyr  = ((pk2 >> 15) & 1) * 96;
            #pragma unroll
            for (int ch = 0; ch < 2; ++ch) {
                #pragma unroll
                for (int j = 0; j < 8; ++j) {
                    int c = ch * 32 + q * 8 + j;
                    const float* xc = xb + (size_t)c * HW + a00p;
                    float v = fmaf(w4x, xc[0],
                              fmaf(w4y, xc[dxv],
                              fmaf(w4z, xc[dyr],
                                   w4w * xc[dyr + dxv])));
                    if (ch) bq1[j] = f2bf(v); else bq0[j] = f2bf(v);
                }
            }
        }

        // A fragments: dense 1024B wave-loads from fragment-major wfrag
        const short* wkc = wlane + (size_t)kk * 1024;     // [mt][kk][ch]...
        short8 a00 = *(const short8*)(wkc + 0 * 9216);
        short8 a10 = *(const short8*)(wkc + 1 * 9216);
        short8 a20 = *(const short8*)(wkc + 2 * 9216);
        short8 a30 = *(const short8*)(wkc + 3 * 9216);
        acc0 = __builtin_amdgcn_mfma_f32_16x16x32_bf16(a00, bq0, acc0, 0, 0, 0);
        acc1 = __builtin_amdgcn_mfma_f32_16x16x32_bf16(a10, bq0, acc1, 0, 0, 0);
        acc2 = __builtin_amdgcn_mfma_f32_16x16x32_bf16(a20, bq0, acc2, 0, 0, 0);
        acc3 = __builtin_amdgcn_mfma_f32_16x16x32_bf16(a30, bq0, acc3, 0, 0, 0);
        short8 a01 = *(const short8*)(wkc + 512 + 0 * 9216);
        short8 a11 = *(const short8*)(wkc + 512 + 1 * 9216);
        short8 a21 = *(const short8*)(wkc + 512 + 2 * 9216);
        short8 a31 = *(const short8*)(wkc + 512 + 3 * 9216);
        acc0 = __builtin_amdgcn_mfma_f32_16x16x32_bf16(a01, bq1, acc0, 0, 0, 0);
        acc1 = __builtin_amdgcn_mfma_f32_16x16x32_bf16(a11, bq1, acc1, 0, 0, 0);
        acc2 = __builtin_amdgcn_mfma_f32_16x16x32_bf16(a21, bq1, acc2, 0, 0, 0);
        acc3 = __builtin_amdgcn_mfma_f32_16x16x32_bf16(a31, bq1, acc3, 0, 0, 0);
    }

    // ---- Epilogue: stage through LDS (aliases window) for dense stores ----
    __syncthreads();                       // all window reads done; reuse smem
    float* sC = (float*)smem;              // [64][68] floats = 17.4 KB
    #pragma unroll
    for (int mt = 0; mt < 4; ++mt) {
        float4v a = (mt == 0) ? acc0 : (mt == 1) ? acc1 : (mt == 2) ? acc2 : acc3;
        int cout = mt * 16 + q * 4;
        #pragma unroll
        for (int reg = 0; reg < 4; ++reg)
            sC[(cout + reg) * 68 + plw] = a[reg];
    }
    __syncthreads();

    #pragma unroll
    for (int i = 0; i < 4; ++i) {
        int idx  = i * NT + tid;
        int cout = idx >> 4;
        int px4  = (idx & 15) * 4;         // local pixel 0..60
        int row  = px4 >> 4;
        int col  = px4 & 15;
        float4 v = *(const float4*)&sC[cout * 68 + px4];
        *(float4*)&out[((size_t)(b * COUTn + cout)) * HW + (ty0 + row) * 96 + tx0 + col] = v;
    }
}

extern "C" void kernel_launch(void* const* d_in, const int* in_sizes, int n_in,
                              void* d_out, int out_size, void* d_ws, size_t ws_size,
                              hipStream_t stream) {
    const float* x      = (const float*)d_in[0];
    const float* offset = (const float*)d_in[1];
    const float* weight = (const float*)d_in[2];
    float* out = (float*)d_out;
    short* wfrag = (short*)d_ws;   // 73,728 B

    prep_weight<<<dim3((COUTn * KDIM + NT - 1) / NT), dim3(NT), 0, stream>>>(weight, wfrag);
    deform_conv_win<<<dim3(Bn * BLKS_PER_IMG), dim3(NT), 0, stream>>>(x, offset, wfrag, out);
}

// Round 8
// 103.959 us; speedup vs baseline: 2.4039x; 1.0573x over previous
//
#include <hip/hip_runtime.h>

// Problem constants
#define Bn     8
#define Cn     64
#define Hn     96
#define Wn     96
#define HW     9216        // Hn*Wn
#define K2     9
#define COUTn  64
#define KDIM   576         // Cn*K2
#define NT     256
// Tile geometry: 16 wide x 4 tall = 64 pixels/block
#define TW     16
#define TH     4
#define TILES_X 6
#define BLKS_PER_IMG 144   // (96/16)*(96/4)
#define BLK_PIX 64
// LDS window: 24 cols x 12 rows of 128B f16 records, padded to 144B stride
#define WW     24
#define WH     12
#define WSTR   144                 // bytes per record in LDS (pad 16)
#define WDY    (WW*WSTR)           // 3456 = +1 row step
#define WIN_BYTES (WW*WH*WSTR)     // 41472

typedef __attribute__((ext_vector_type(8))) _Float16 half8;    // 16 B = 4 VGPR
typedef __attribute__((ext_vector_type(4))) _Float16 half4v;   // 8 B
typedef __attribute__((ext_vector_type(4))) float    float4v;  // MFMA acc

// ---- Pre-pass: weight -> f16 fragment-major ----
// wfrag layout: [mt(4)][kk(9)][ch(2)][lane(64)][j(8)]: A-fragment wave-load is
// 1024B contiguous. element: m=lane&15, q=lane>>4; cout=mt*16+m; c=ch*32+q*8+j.
__global__ void prep_weight(const float* __restrict__ w, _Float16* __restrict__ wfrag) {
    int i = blockIdx.x * NT + threadIdx.x;
    if (i < COUTn * KDIM) {
        int j    = i & 7;
        int lane = (i >> 3) & 63;
        int ch   = (i >> 9) & 1;
        int mk   = i >> 10;          // mt*9 + kk
        int kk   = mk % 9;
        int mt   = mk / 9;
        int m = lane & 15, q = lane >> 4;
        int cout = mt * 16 + m;
        int c    = ch * 32 + q * 8 + j;
        wfrag[i] = (_Float16)w[cout * KDIM + c * K2 + kk];
    }
}

// ---- Main kernel: stage NCHW f32 window -> LDS f16 HWC, packed-f16 bilinear ----
__global__ __launch_bounds__(NT, 3)
void deform_conv_win(const float* __restrict__ x,
                     const float* __restrict__ offset,
                     const _Float16* __restrict__ wfrag,
                     float* __restrict__ out) {
    __shared__ __align__(16) char smem[WIN_BYTES];  // 41.5 KB window; epilogue sC aliases
    __shared__ int    sA [K2 * BLK_PIX];   // 2.25 KB: LDS off | dx | dy | ok
    __shared__ int    sA2[K2 * BLK_PIX];   // 2.25 KB: global pack (fallback)
    __shared__ half4v sWh[K2 * BLK_PIX];   // 4.5 KB bilinear weights (f16)

    const int tid  = threadIdx.x;
    const int b    = blockIdx.x & 7;                 // XCD swizzle
    const int tl   = blockIdx.x >> 3;
    const int ty0  = (tl / TILES_X) * TH;
    const int tx0  = (tl % TILES_X) * TW;
    const int wy0  = min(max(ty0 - 4, 0), Hn - WH);  // window origin (in-image)
    const int wx0  = min(max(tx0 - 4, 0), Wn - WW);

    const float* xb   = x + (size_t)b * (Cn * HW);
    const float* offb = offset + (size_t)b * (2 * K2 * HW);

    const int lane = tid & 63;
    const int wv   = tid >> 6;

    // ---- Phase 0a: sampling metadata per (kk, pixel) ----
    for (int e = tid; e < K2 * BLK_PIX; e += NT) {
        int kk = e >> 6;
        int pl = e & 63;
        int h = ty0 + (pl >> 4);
        int w = tx0 + (pl & 15);
        int pix = h * 96 + w;
        float offy = offb[(2 * kk) * HW + pix];
        float offx = offb[(2 * kk + 1) * HW + pix];
        float py = (float)(h - 1 + kk / 3) + offy;
        float px = (float)(w - 1 + kk % 3) + offx;
        float y0f = floorf(py), x0f = floorf(px);
        float ly = py - y0f, lx = px - x0f;
        int y0 = (int)y0f, x0 = (int)x0f;
        float vy0 = ((unsigned)y0 < 96u) ? 1.f : 0.f;
        float vy1 = ((unsigned)(y0 + 1) < 96u) ? 1.f : 0.f;
        float vx0 = ((unsigned)x0 < 96u) ? 1.f : 0.f;
        float vx1 = ((unsigned)(x0 + 1) < 96u) ? 1.f : 0.f;
        float w00 = (1.f - ly) * (1.f - lx) * vy0 * vx0;
        float w01 = (1.f - ly) * lx         * vy0 * vx1;
        float w10 = ly * (1.f - lx)         * vy1 * vx0;
        float w11 = ly * lx                 * vy1 * vx1;
        int y0c = min(max(y0, 0), 95);
        int x0c = min(max(x0, 0), 95);
        int dx = min(max(x0 + 1, 0), 95) - x0c;   // 0 or 1
        int dy = min(max(y0 + 1, 0), 95) - y0c;   // 0 or 1
        int ok = (y0c >= wy0) & (y0c + dy <= wy0 + WH - 1) &
                 (x0c >= wx0) & (x0c + dx <= wx0 + WW - 1);
        int woff = ok ? ((y0c - wy0) * WW + (x0c - wx0)) * WSTR : 0;
        sA [e] = woff | (dx << 16) | (dy << 17) | (ok << 18);
        sA2[e] = (y0c * 96 + x0c) | (dx << 14) | (dy << 15);
        half4v hv;
        hv[0] = (_Float16)w00; hv[1] = (_Float16)w01;
        hv[2] = (_Float16)w10; hv[3] = (_Float16)w11;
        sWh[e] = hv;
    }

    // ---- Phase 0b: stage 24x12 window from NCHW f32 -> LDS f16 HWC ----
    // lane = channel (global dwordx4 strided across c-planes, L2-resident);
    // LDS b16 writes are 64-lane contiguous (2 lanes/bank = free).
    {
        const float* xg = xb + (size_t)lane * HW + wy0 * 96 + wx0;
        #pragma unroll
        for (int p2 = 0; p2 < 18; ++p2) {
            int idx2 = p2 * 4 + wv;           // 0..71 = row*6 + colgroup
            int row  = idx2 / 6;
            int c4   = (idx2 - row * 6) * 4;  // col 0,4,8,12,16,20
            float4 v = *(const float4*)(xg + row * 96 + c4);
            char* dst = smem + (row * WW + c4) * WSTR + lane * 2;
            *(_Float16*)(dst + 0 * WSTR) = (_Float16)v.x;
            *(_Float16*)(dst + 1 * WSTR) = (_Float16)v.y;
            *(_Float16*)(dst + 2 * WSTR) = (_Float16)v.z;
            *(_Float16*)(dst + 3 * WSTR) = (_Float16)v.w;
        }
    }
    __syncthreads();

    const int q    = lane >> 4;          // quad 0..3
    const int r    = lane & 15;          // 0..15
    const int plw  = wv * 16 + r;        // B-column pixel (local)

    float4v acc0 = {0.f,0.f,0.f,0.f};
    float4v acc1 = {0.f,0.f,0.f,0.f};
    float4v acc2 = {0.f,0.f,0.f,0.f};
    float4v acc3 = {0.f,0.f,0.f,0.f};

    const _Float16* wlane = wfrag + lane * 8;

    for (int kk = 0; kk < 9; ++kk) {
        const int idx = kk * BLK_PIX + plw;
        const int pk  = sA[idx];
        const half4v hv = sWh[idx];
        const _Float16 w0 = hv[0], w1 = hv[1], w2 = hv[2], w3 = hv[3];

        half8 bq0, bq1;
        if (pk & (1 << 18)) {
            // LDS window path (always taken for this data); packed v_pk_fma_f16
            const char* base = smem + (pk & 0xFFFF) + q * 16;
            const int dxs = ((pk >> 16) & 1) * WSTR;
            const int dys = ((pk >> 17) & 1) * WDY;
            half8 s00a = *(const half8*)(base);
            half8 s01a = *(const half8*)(base + dxs);
            half8 s10a = *(const half8*)(base + dys);
            half8 s11a = *(const half8*)(base + dys + dxs);
            half8 s00b = *(const half8*)(base + 64);
            half8 s01b = *(const half8*)(base + 64 + dxs);
            half8 s10b = *(const half8*)(base + 64 + dys);
            half8 s11b = *(const half8*)(base + 64 + dys + dxs);
            bq0 = s00a * w0 + s01a * w1 + s10a * w2 + s11a * w3;
            bq1 = s00b * w0 + s01b * w1 + s10b * w2 + s11b * w3;
        } else {
            // Global f32 fallback (pathological offsets only; correct, slow)
            const int pk2  = sA2[idx];
            const int a00p = pk2 & 16383;
            const int dxv  = (pk2 >> 14) & 1;
            const int dyr  = ((pk2 >> 15) & 1) * 96;
            const float f0 = (float)w0, f1 = (float)w1, f2 = (float)w2, f3 = (float)w3;
            #pragma unroll
            for (int ch = 0; ch < 2; ++ch) {
                #pragma unroll
                for (int j = 0; j < 8; ++j) {
                    int c = ch * 32 + q * 8 + j;
                    const float* xc = xb + (size_t)c * HW + a00p;
                    float v = fmaf(f0, xc[0],
                              fmaf(f1, xc[dxv],
                              fmaf(f2, xc[dyr],
                                   f3 * xc[dyr + dxv])));
                    if (ch) bq1[j] = (_Float16)v; else bq0[j] = (_Float16)v;
                }
            }
        }

        // A fragments: dense 1024B wave-loads from fragment-major wfrag
        const _Float16* wkc = wlane + (size_t)kk * 1024;     // [mt][kk][ch]...
        half8 a00 = *(const half8*)(wkc + 0 * 9216);
        half8 a10 = *(const half8*)(wkc + 1 * 9216);
        half8 a20 = *(const half8*)(wkc + 2 * 9216);
        half8 a30 = *(const half8*)(wkc + 3 * 9216);
        acc0 = __builtin_amdgcn_mfma_f32_16x16x32_f16(a00, bq0, acc0, 0, 0, 0);
        acc1 = __builtin_amdgcn_mfma_f32_16x16x32_f16(a10, bq0, acc1, 0, 0, 0);
        acc2 = __builtin_amdgcn_mfma_f32_16x16x32_f16(a20, bq0, acc2, 0, 0, 0);
        acc3 = __builtin_amdgcn_mfma_f32_16x16x32_f16(a30, bq0, acc3, 0, 0, 0);
        half8 a01 = *(const half8*)(wkc + 512 + 0 * 9216);
        half8 a11 = *(const half8*)(wkc + 512 + 1 * 9216);
        half8 a21 = *(const half8*)(wkc + 512 + 2 * 9216);
        half8 a31 = *(const half8*)(wkc + 512 + 3 * 9216);
        acc0 = __builtin_amdgcn_mfma_f32_16x16x32_f16(a01, bq1, acc0, 0, 0, 0);
        acc1 = __builtin_amdgcn_mfma_f32_16x16x32_f16(a11, bq1, acc1, 0, 0, 0);
        acc2 = __builtin_amdgcn_mfma_f32_16x16x32_f16(a21, bq1, acc2, 0, 0, 0);
        acc3 = __builtin_amdgcn_mfma_f32_16x16x32_f16(a31, bq1, acc3, 0, 0, 0);
    }

    // ---- Epilogue: stage through LDS (aliases window) for dense stores ----
    __syncthreads();                       // all window reads done; reuse smem
    float* sC = (float*)smem;              // [64][68] floats = 17.4 KB
    #pragma unroll
    for (int mt = 0; mt < 4; ++mt) {
        float4v a = (mt == 0) ? acc0 : (mt == 1) ? acc1 : (mt == 2) ? acc2 : acc3;
        int cout = mt * 16 + q * 4;
        #pragma unroll
        for (int reg = 0; reg < 4; ++reg)
            sC[(cout + reg) * 68 + plw] = a[reg];
    }
    __syncthreads();

    #pragma unroll
    for (int i = 0; i < 4; ++i) {
        int idx  = i * NT + tid;
        int cout = idx >> 4;
        int px4  = (idx & 15) * 4;         // local pixel 0..60
        int row  = px4 >> 4;
        int col  = px4 & 15;
        float4 v = *(const float4*)&sC[cout * 68 + px4];
        *(float4*)&out[((size_t)(b * COUTn + cout)) * HW + (ty0 + row) * 96 + tx0 + col] = v;
    }
}

extern "C" void kernel_launch(void* const* d_in, const int* in_sizes, int n_in,
                              void* d_out, int out_size, void* d_ws, size_t ws_size,
                              hipStream_t stream) {
    const float* x      = (const float*)d_in[0];
    const float* offset = (const float*)d_in[1];
    const float* weight = (const float*)d_in[2];
    float* out = (float*)d_out;
    _Float16* wfrag = (_Float16*)d_ws;   // 73,728 B

    prep_weight<<<dim3((COUTn * KDIM + NT - 1) / NT), dim3(NT), 0, stream>>>(weight, wfrag);
    deform_conv_win<<<dim3(Bn * BLKS_PER_IMG), dim3(NT), 0, stream>>>(x, offset, wfrag, out);
}

// Round 9
// 96.435 us; speedup vs baseline: 2.5915x; 1.0780x over previous
//
#include <hip/hip_runtime.h>

// Problem constants
#define Bn     8
#define Cn     64
#define Hn     96
#define Wn     96
#define HW     9216        // Hn*Wn
#define K2     9
#define COUTn  64
#define KDIM   576         // Cn*K2
#define NT     256
#define RECS   64          // f16 per HWC pixel record (128 B)
#define XH_HALFS ((size_t)Bn*HW*RECS)
#define XH_BYTES (XH_HALFS*2)              // 9,437,184
// Tile geometry: 16 wide x 4 tall = 64 pixels/block
#define TW     16
#define TH     4
#define TILES_X 6
#define BLKS_PER_IMG 144   // (96/16)*(96/4)
#define BLK_PIX 64
// LDS window: 24 cols x 12 rows of 128B f16 records, padded to 144B stride
#define WW     24
#define WH     12
#define WSTR   144                 // bytes per record in LDS (pad 16)
#define WDY    (WW*WSTR)           // 3456 = +1 row step
#define WIN_BYTES (WW*WH*WSTR)     // 41472
#define WCHUNKS (WW*WH*8)          // 2304 16B chunks = 9 per thread

typedef __attribute__((ext_vector_type(8))) _Float16 half8;    // 16 B = 4 VGPR
typedef __attribute__((ext_vector_type(4))) _Float16 half4v;   // 8 B
typedef __attribute__((ext_vector_type(4))) float    float4v;  // MFMA acc

// ---- Fused pre-pass: x NCHW f32 -> HWC f16 global; weight -> f16 frag-major ----
// wfrag layout: [mt(4)][kk(9)][ch(2)][lane(64)][j(8)]: A-fragment wave-load is
// 1024B contiguous. element: m=lane&15, q=lane>>4; cout=mt*16+m; c=ch*32+q*8+j.
__global__ __launch_bounds__(NT)
void prep_all(const float* __restrict__ x, _Float16* __restrict__ xh,
              const float* __restrict__ w, _Float16* __restrict__ wfrag) {
    const int blk = blockIdx.x;
    if (blk >= Bn * BLKS_PER_IMG) {
        int i = (blk - Bn * BLKS_PER_IMG) * NT + threadIdx.x;
        if (i < COUTn * KDIM) {
            int j    = i & 7;
            int lane = (i >> 3) & 63;
            int ch   = (i >> 9) & 1;
            int mk   = i >> 10;          // mt*9 + kk
            int kk   = mk % 9;
            int mt   = mk / 9;
            int m = lane & 15, q = lane >> 4;
            int cout = mt * 16 + m;
            int c    = ch * 32 + q * 8 + j;
            wfrag[i] = (_Float16)w[cout * KDIM + c * K2 + kk];
        }
        return;
    }
    __shared__ float tile[Cn * 65];     // 16.6 KB
    const int t    = threadIdx.x;
    const int lane = t & 63, wv = t >> 6;
    const int b    = blk & 7;
    const int pix0 = (blk >> 3) * BLK_PIX;   // linear 64-pixel groups

    #pragma unroll
    for (int i = 0; i < 16; ++i) {
        int c = wv + i * 4;
        tile[c * 65 + lane] = x[((size_t)b * Cn + c) * HW + pix0 + lane];
    }
    __syncthreads();
    #pragma unroll
    for (int pass = 0; pass < 4; ++pass) {
        int px = wv * 16 + pass * 4 + (lane >> 4);
        int c4 = (lane & 15) * 4;
        half4v v;
        v[0] = (_Float16)tile[(c4 + 0) * 65 + px];
        v[1] = (_Float16)tile[(c4 + 1) * 65 + px];
        v[2] = (_Float16)tile[(c4 + 2) * 65 + px];
        v[3] = (_Float16)tile[(c4 + 3) * 65 + px];
        *(half4v*)&xh[((size_t)b * HW + pix0 + px) * RECS + c4] = v;
    }
}

// ---- Main kernel: dense HWC-f16 window staging, packed-f16 bilinear, f16 MFMA ----
__global__ __launch_bounds__(NT, 3)
void deform_conv_win(const float* __restrict__ x,          // NCHW f32 (fallback only)
                     const _Float16* __restrict__ xh,      // HWC f16
                     const float* __restrict__ offset,
                     const _Float16* __restrict__ wfrag,
                     float* __restrict__ out) {
    __shared__ __align__(16) char smem[WIN_BYTES];  // 41.5 KB window; epilogue sC aliases
    __shared__ int    sA [K2 * BLK_PIX];   // 2.25 KB: LDS off | dx | dy | ok
    __shared__ int    sA2[K2 * BLK_PIX];   // 2.25 KB: global pack (fallback)
    __shared__ half4v sWh[K2 * BLK_PIX];   // 4.5 KB bilinear weights (f16)

    const int tid  = threadIdx.x;
    const int b    = blockIdx.x & 7;                 // XCD swizzle
    const int tl   = blockIdx.x >> 3;
    const int ty0  = (tl / TILES_X) * TH;
    const int tx0  = (tl % TILES_X) * TW;
    const int wy0  = min(max(ty0 - 4, 0), Hn - WH);  // window origin (in-image)
    const int wx0  = min(max(tx0 - 4, 0), Wn - WW);

    const float* xb   = x + (size_t)b * (Cn * HW);
    const float* offb = offset + (size_t)b * (2 * K2 * HW);

    const int lane = tid & 63;
    const int wv   = tid >> 6;

    // ---- Phase 0a: sampling metadata per (kk, pixel) ----
    for (int e = tid; e < K2 * BLK_PIX; e += NT) {
        int kk = e >> 6;
        int pl = e & 63;
        int h = ty0 + (pl >> 4);
        int w = tx0 + (pl & 15);
        int pix = h * 96 + w;
        float offy = offb[(2 * kk) * HW + pix];
        float offx = offb[(2 * kk + 1) * HW + pix];
        float py = (float)(h - 1 + kk / 3) + offy;
        float px = (float)(w - 1 + kk % 3) + offx;
        float y0f = floorf(py), x0f = floorf(px);
        float ly = py - y0f, lx = px - x0f;
        int y0 = (int)y0f, x0 = (int)x0f;
        float vy0 = ((unsigned)y0 < 96u) ? 1.f : 0.f;
        float vy1 = ((unsigned)(y0 + 1) < 96u) ? 1.f : 0.f;
        float vx0 = ((unsigned)x0 < 96u) ? 1.f : 0.f;
        float vx1 = ((unsigned)(x0 + 1) < 96u) ? 1.f : 0.f;
        float w00 = (1.f - ly) * (1.f - lx) * vy0 * vx0;
        float w01 = (1.f - ly) * lx         * vy0 * vx1;
        float w10 = ly * (1.f - lx)         * vy1 * vx0;
        float w11 = ly * lx                 * vy1 * vx1;
        int y0c = min(max(y0, 0), 95);
        int x0c = min(max(x0, 0), 95);
        int dx = min(max(x0 + 1, 0), 95) - x0c;   // 0 or 1
        int dy = min(max(y0 + 1, 0), 95) - y0c;   // 0 or 1
        int ok = (y0c >= wy0) & (y0c + dy <= wy0 + WH - 1) &
                 (x0c >= wx0) & (x0c + dx <= wx0 + WW - 1);
        int woff = ok ? ((y0c - wy0) * WW + (x0c - wx0)) * WSTR : 0;
        sA [e] = woff | (dx << 16) | (dy << 17) | (ok << 18);
        sA2[e] = (y0c * 96 + x0c) | (dx << 14) | (dy << 15);
        half4v hv;
        hv[0] = (_Float16)w00; hv[1] = (_Float16)w01;
        hv[2] = (_Float16)w10; hv[3] = (_Float16)w11;
        sWh[e] = hv;
    }

    // ---- Phase 0b: stage 24x12 window from HWC f16 (dense, 16 lines/wave-instr) ----
    {
        const _Float16* src = xh + ((size_t)b * HW + wy0 * 96 + wx0) * RECS;
        #pragma unroll
        for (int i = 0; i < 9; ++i) {
            int c   = i * NT + tid;         // 0..2303
            int rec = c >> 3;
            int w16 = c & 7;
            int row = rec / WW;
            int col = rec - row * WW;
            const _Float16* g = src + ((size_t)row * 96 + col) * RECS + w16 * 8;
            *(half8*)(smem + rec * WSTR + w16 * 16) = *(const half8*)g;
        }
    }
    __syncthreads();

    const int q    = lane >> 4;          // quad 0..3
    const int r    = lane & 15;          // 0..15
    const int plw  = wv * 16 + r;        // B-column pixel (local)

    float4v acc0 = {0.f,0.f,0.f,0.f};
    float4v acc1 = {0.f,0.f,0.f,0.f};
    float4v acc2 = {0.f,0.f,0.f,0.f};
    float4v acc3 = {0.f,0.f,0.f,0.f};

    const _Float16* wlane = wfrag + lane * 8;

    for (int kk = 0; kk < 9; ++kk) {
        const int idx = kk * BLK_PIX + plw;
        const int pk  = sA[idx];
        const half4v hv = sWh[idx];
        const _Float16 w0 = hv[0], w1 = hv[1], w2 = hv[2], w3 = hv[3];

        half8 bq0, bq1;
        if (pk & (1 << 18)) {
            // LDS window path (always taken for this data); packed v_pk_fma_f16
            const char* base = smem + (pk & 0xFFFF) + q * 16;
            const int dxs = ((pk >> 16) & 1) * WSTR;
            const int dys = ((pk >> 17) & 1) * WDY;
            half8 s00a = *(const half8*)(base);
            half8 s01a = *(const half8*)(base + dxs);
            half8 s10a = *(const half8*)(base + dys);
            half8 s11a = *(const half8*)(base + dys + dxs);
            half8 s00b = *(const half8*)(base + 64);
            half8 s01b = *(const half8*)(base + 64 + dxs);
            half8 s10b = *(const half8*)(base + 64 + dys);
            half8 s11b = *(const half8*)(base + 64 + dys + dxs);
            bq0 = s00a * w0 + s01a * w1 + s10a * w2 + s11a * w3;
            bq1 = s00b * w0 + s01b * w1 + s10b * w2 + s11b * w3;
        } else {
            // Global f32 fallback (pathological offsets only; correct, slow)
            const int pk2  = sA2[idx];
            const int a00p = pk2 & 16383;
            const int dxv  = (pk2 >> 14) & 1;
            const int dyr  = ((pk2 >> 15) & 1) * 96;
            const float f0 = (float)w0, f1 = (float)w1, f2 = (float)w2, f3 = (float)w3;
            #pragma unroll
            for (int ch = 0; ch < 2; ++ch) {
                #pragma unroll
                for (int j = 0; j < 8; ++j) {
                    int c = ch * 32 + q * 8 + j;
                    const float* xc = xb + (size_t)c * HW + a00p;
                    float v = fmaf(f0, xc[0],
                              fmaf(f1, xc[dxv],
                              fmaf(f2, xc[dyr],
                                   f3 * xc[dyr + dxv])));
                    if (ch) bq1[j] = (_Float16)v; else bq0[j] = (_Float16)v;
                }
            }
        }

        // A fragments: dense 1024B wave-loads from fragment-major wfrag
        const _Float16* wkc = wlane + (size_t)kk * 1024;     // [mt][kk][ch]...
        half8 a00 = *(const half8*)(wkc + 0 * 9216);
        half8 a10 = *(const half8*)(wkc + 1 * 9216);
        half8 a20 = *(const half8*)(wkc + 2 * 9216);
        half8 a30 = *(const half8*)(wkc + 3 * 9216);
        acc0 = __builtin_amdgcn_mfma_f32_16x16x32_f16(a00, bq0, acc0, 0, 0, 0);
        acc1 = __builtin_amdgcn_mfma_f32_16x16x32_f16(a10, bq0, acc1, 0, 0, 0);
        acc2 = __builtin_amdgcn_mfma_f32_16x16x32_f16(a20, bq0, acc2, 0, 0, 0);
        acc3 = __builtin_amdgcn_mfma_f32_16x16x32_f16(a30, bq0, acc3, 0, 0, 0);
        half8 a01 = *(const half8*)(wkc + 512 + 0 * 9216);
        half8 a11 = *(const half8*)(wkc + 512 + 1 * 9216);
        half8 a21 = *(const half8*)(wkc + 512 + 2 * 9216);
        half8 a31 = *(const half8*)(wkc + 512 + 3 * 9216);
        acc0 = __builtin_amdgcn_mfma_f32_16x16x32_f16(a01, bq1, acc0, 0, 0, 0);
        acc1 = __builtin_amdgcn_mfma_f32_16x16x32_f16(a11, bq1, acc1, 0, 0, 0);
        acc2 = __builtin_amdgcn_mfma_f32_16x16x32_f16(a21, bq1, acc2, 0, 0, 0);
        acc3 = __builtin_amdgcn_mfma_f32_16x16x32_f16(a31, bq1, acc3, 0, 0, 0);
    }

    // ---- Epilogue: stage through LDS (aliases window) for dense stores ----
    __syncthreads();                       // all window reads done; reuse smem
    float* sC = (float*)smem;              // [64][68] floats = 17.4 KB
    #pragma unroll
    for (int mt = 0; mt < 4; ++mt) {
        float4v a = (mt == 0) ? acc0 : (mt == 1) ? acc1 : (mt == 2) ? acc2 : acc3;
        int cout = mt * 16 + q * 4;
        #pragma unroll
        for (int reg = 0; reg < 4; ++reg)
            sC[(cout + reg) * 68 + plw] = a[reg];
    }
    __syncthreads();

    #pragma unroll
    for (int i = 0; i < 4; ++i) {
        int idx  = i * NT + tid;
        int cout = idx >> 4;
        int px4  = (idx & 15) * 4;         // local pixel 0..60
        int row  = px4 >> 4;
        int col  = px4 & 15;
        float4 v = *(const float4*)&sC[cout * 68 + px4];
        *(float4*)&out[((size_t)(b * COUTn + cout)) * HW + (ty0 + row) * 96 + tx0 + col] = v;
    }
}

extern "C" void kernel_launch(void* const* d_in, const int* in_sizes, int n_in,
                              void* d_out, int out_size, void* d_ws, size_t ws_size,
                              hipStream_t stream) {
    const float* x      = (const float*)d_in[0];
    const float* offset = (const float*)d_in[1];
    const float* weight = (const float*)d_in[2];
    float* out = (float*)d_out;

    _Float16* xh    = (_Float16*)d_ws;                          // 9,437,184 B
    _Float16* wfrag = (_Float16*)((char*)d_ws + XH_BYTES);      // 73,728 B

    prep_all<<<dim3(Bn * BLKS_PER_IMG + 144), dim3(NT), 0, stream>>>(x, xh, weight, wfrag);
    deform_conv_win<<<dim3(Bn * BLKS_PER_IMG), dim3(NT), 0, stream>>>(x, xh, offset, wfrag, out);
}